// Round 18
// baseline (114.342 us; speedup 1.0000x reference)
//
#include <hip/hip_runtime.h>
#include <math.h>

#define S 2048
#define D 1024
#define NH 16
#define HD 32
#define HD2 64

static constexpr float SCALE_Q_EXP2  = 0.17677669529663687f * 1.4426950408889634f; // *log2(e)
static constexpr float LAMBDA_INIT_F = 0.78360576653162450f;   // 0.8 - 0.6*exp(-3.6)
static constexpr float ONE_MINUS_LI  = 0.21639423346837553f;

typedef unsigned short u16;
typedef unsigned int   u32;
typedef __attribute__((ext_vector_type(4)))  unsigned short u16x4;
typedef __attribute__((ext_vector_type(8)))  short          bfrag;   // 8 bf16 = 4 VGPR
typedef __attribute__((ext_vector_type(16))) float          f16acc;  // MFMA 32x32 accumulator
typedef __attribute__((ext_vector_type(4)))  unsigned int   uint4v;

__device__ __forceinline__ u16 f2bf(float f) {                 // RNE f32->bf16
    u32 u = __builtin_bit_cast(u32, f);
    return (u16)((u + 0x7FFFu + ((u >> 16) & 1u)) >> 16);
}
__device__ __forceinline__ f16acc fillv(float v) {
    f16acc z;
#pragma unroll
    for (int i = 0; i < 16; ++i) z[i] = v;
    return z;
}
// single-instruction exp2, hazard-safe via builtin (round 14 verified)
__device__ __forceinline__ float exp2_raw(float x) {
#if __has_builtin(__builtin_amdgcn_exp2f)
    return __builtin_amdgcn_exp2f(x);
#else
    float r;
    asm volatile("v_exp_f32 %0, %1\n\ts_nop 1" : "=v"(r) : "v"(x));
    return r;
#endif
}
#define MFMA(a, b, c) __builtin_amdgcn_mfma_f32_32x32x16_bf16(a, b, c, 0, 0, 0)

__device__ __forceinline__ void gload16(const u16* src, u16* lds) {
    __builtin_amdgcn_global_load_lds((const __attribute__((address_space(1))) void*)src,
                                     (__attribute__((address_space(3))) void*)lds, 16, 0, 0);
}

// ---------------- prep: trig tables (bit-matching the f32 numpy/jax pipeline) ----------------
__global__ void prep_kernel(const float* __restrict__ lq1, const float* __restrict__ lk1,
                            const float* __restrict__ lq2, const float* __restrict__ lk2,
                            float* __restrict__ cosT, float* __restrict__ sinT,
                            float* __restrict__ lamOut) {
    int idx = blockIdx.x * blockDim.x + threadIdx.x;
    if (idx < S * 16) {
        int p = idx >> 4;
        int m = idx & 15;
        const double base = (double)1.0e-4f;
        float pf   = (float)pow(base, (double)m * (1.0 / 16.0));  // == powf(1e-4f, m/16), CR
        float freq = 1.0f / pf;                                   // f32 division
        float angf = (float)p * freq;                             // exact f32 multiply
        double a = (double)angf;
        cosT[idx] = (float)cos(a);
        sinT[idx] = (float)sin(a);
    }
    if (blockIdx.x == 0 && threadIdx.x == 0) {
        float s1 = 0.f, s2 = 0.f;
        for (int i = 0; i < HD; ++i) {
            s1 += lq1[i] * lk1[i];
            s2 += lq2[i] * lk2[i];
        }
        *lamOut = expf(s1) - expf(s2) + LAMBDA_INIT_F;
    }
}

// ---------------- convert: x -> bf16; W -> bf16 transposed [n][k] (LDS-tiled) ----------------
__global__ __launch_bounds__(256)
void convert_kernel(const float* __restrict__ x,  const float* __restrict__ Wq,
                    const float* __restrict__ Wk, const float* __restrict__ Wv,
                    const float* __restrict__ Wo,
                    u16* __restrict__ xb,  u16* __restrict__ WqT, u16* __restrict__ WkT,
                    u16* __restrict__ WvT, u16* __restrict__ WoT) {
    const int z = blockIdx.y;
    if (z == 0) {
        const int i = blockIdx.x * 256 + threadIdx.x;
        const float4 v = *(const float4*)&x[(size_t)i * 4];
        u16x4 r; r.x = f2bf(v.x); r.y = f2bf(v.y); r.z = f2bf(v.z); r.w = f2bf(v.w);
        *(u16x4*)&xb[(size_t)i * 4] = r;
        return;
    }
    const int b = blockIdx.x;
    if (b >= 256) return;
    __shared__ u16 Ts[64][66];
    const float* W = (z == 1) ? Wq : (z == 2) ? Wk : (z == 3) ? Wv : Wo;
    u16* T = (z == 1) ? WqT : (z == 2) ? WkT : (z == 3) ? WvT : WoT;
    const int k0 = (b >> 4) * 64, n0 = (b & 15) * 64;
    const int rg = threadIdx.x >> 4, cc = (threadIdx.x & 15) * 4;
#pragma unroll
    for (int i = 0; i < 4; ++i) {
        const int r = rg * 4 + i;
        const float4 v = *(const float4*)&W[(size_t)(k0 + r) * D + n0 + cc];
        Ts[r][cc + 0] = f2bf(v.x); Ts[r][cc + 1] = f2bf(v.y);
        Ts[r][cc + 2] = f2bf(v.z); Ts[r][cc + 3] = f2bf(v.w);
    }
    __syncthreads();
#pragma unroll
    for (int i = 0; i < 4; ++i) {
        const int rn = rg * 4 + i;
        u16x4 res;
        res.x = Ts[cc + 0][rn]; res.y = Ts[cc + 1][rn];
        res.z = Ts[cc + 2][rn]; res.w = Ts[cc + 3][rn];
        *(u16x4*)&T[(size_t)(n0 + rn) * D + k0 + cc] = res;
    }
}

// ---------------- bf16 MFMA GEMM, 128x128 tile, BK=32, 4 waves (m97 structure) ----------------
// MODE 0: Q -> Qb row layout (RoPE+scale into exp2 domain);
//         K -> Kb2 [h2][64 chunks][4 dim-octet planes][32 key][8 u16]  (stride 1024/chunk);
//         V -> VT2 [h][64 chunks][8 (dt,key-octet) planes][32 d][8 u16] (stride 2048/chunk).
template<int MODE>
__global__ __launch_bounds__(256)
void mm_kernel(const u16* __restrict__ Ab, const u16* __restrict__ B0,
               const u16* __restrict__ B1, const u16* __restrict__ B2,
               const float* __restrict__ cosT, const float* __restrict__ sinT,
               u16* __restrict__ Qb, u16* __restrict__ Kb2, u16* __restrict__ VT,
               float* __restrict__ Of) {
    __shared__ u16 As[128 * 32];
    __shared__ u16 Bs[128 * 32];

    const int nb   = blockIdx.x;
    const int row0 = blockIdx.y * 128;
    const int tid  = threadIdx.x;
    const int wave = tid >> 6;
    const int lane = tid & 63;
    const int ql   = lane & 31;
    const int hi   = lane >> 5;
    const int wr   = wave >> 1;
    const int wc   = wave & 1;

    const u16* Bt;
    int col0B;
    if (MODE == 0) {
        Bt = (nb < 8) ? B0 : (nb < 16) ? B1 : B2;
        col0B = (nb & 7) * 128;
    } else {
        Bt = B0;
        col0B = nb * 128;
    }

    const int rIn  = lane >> 2;
    const int kof  = 8 * (lane & 3);
    const size_t aRow0 = (size_t)(row0 + 16 * wave       + rIn) * D + kof;
    const size_t aRow1 = (size_t)(row0 + 16 * (wave + 4) + rIn) * D + kof;
    const size_t bRow0 = (size_t)(col0B + 16 * wave       + rIn) * D + kof;
    const size_t bRow1 = (size_t)(col0B + 16 * (wave + 4) + rIn) * D + kof;
    u16* ldsA0 = &As[512 * wave + 8 * lane];
    u16* ldsA1 = &As[512 * (wave + 4) + 8 * lane];
    u16* ldsB0 = &Bs[512 * wave + 8 * lane];
    u16* ldsB1 = &Bs[512 * (wave + 4) + 8 * lane];

    const int aoff = (wr * 64 + ql) * 32 + hi * 8;
    const int boff = (wc * 64 + ql) * 32 + hi * 8;

    f16acc acc00 = fillv(0.f), acc01 = fillv(0.f), acc10 = fillv(0.f), acc11 = fillv(0.f);

    for (int kk = 0; kk < D; kk += 32) {
        gload16(Ab + aRow0 + kk, ldsA0);
        gload16(Ab + aRow1 + kk, ldsA1);
        gload16(Bt + bRow0 + kk, ldsB0);
        gload16(Bt + bRow1 + kk, ldsB1);
        __syncthreads();
#pragma unroll
        for (int ks = 0; ks < 2; ++ks) {
            const bfrag a0 = *(const bfrag*)&As[aoff + ks * 16];
            const bfrag a1 = *(const bfrag*)&As[aoff + 32 * 32 + ks * 16];
            const bfrag b0 = *(const bfrag*)&Bs[boff + ks * 16];
            const bfrag b1 = *(const bfrag*)&Bs[boff + 32 * 32 + ks * 16];
            acc00 = MFMA(a0, b0, acc00);
            acc01 = MFMA(a0, b1, acc01);
            acc10 = MFMA(a1, b0, acc10);
            acc11 = MFMA(a1, b1, acc11);
        }
        __syncthreads();
    }

    f16acc accA[2][2];
    accA[0][0] = acc00; accA[0][1] = acc01; accA[1][0] = acc10; accA[1][1] = acc11;

    if (MODE == 0 && nb < 8) {           // Q: RoPE + scale, row layout
        const int m = ql >> 1;
        const bool ev = (ql & 1) == 0;
#pragma unroll
        for (int i = 0; i < 2; ++i)
#pragma unroll
        for (int j = 0; j < 2; ++j) {
            const int n = (nb & 7) * 128 + wc * 64 + j * 32 + ql;
            const int head = n >> 5;
            u16* hb = Qb + (size_t)head * S * HD;
#pragma unroll
            for (int r = 0; r < 16; ++r) {
                const int row = row0 + wr * 64 + i * 32 + 4 * hi + (r & 3) + 8 * (r >> 2);
                const float self = accA[i][j][r];
                const float part = __shfl_xor(self, 1);
                const float c = cosT[(row << 4) + m], s = sinT[(row << 4) + m];
                const float res = ev ? (self * c - part * s) : (part * s + self * c);
                hb[(size_t)row * HD + ql] = f2bf(res * SCALE_Q_EXP2);
            }
        }
    } else if (MODE == 0 && nb < 16) {   // K: RoPE, chunk-tiled dim-octet planes
        const int m = ql >> 1;
        const bool ev = (ql & 1) == 0;
#pragma unroll
        for (int i = 0; i < 2; ++i)
#pragma unroll
        for (int j = 0; j < 2; ++j) {
            const int n = (nb & 7) * 128 + wc * 64 + j * 32 + ql;
            const int h2 = n >> 5;
            const int d  = n & 31;
            const int dpl = (d >> 3) * 256 + (d & 7);
            u16* hb = Kb2 + (size_t)h2 * 65536;          // 64 chunks x 1024 u16
#pragma unroll
            for (int r = 0; r < 16; ++r) {
                const int row = row0 + wr * 64 + i * 32 + 4 * hi + (r & 3) + 8 * (r >> 2);
                const float self = accA[i][j][r];
                const float part = __shfl_xor(self, 1);
                const float c = cosT[(row << 4) + m], s = sinT[(row << 4) + m];
                const float res = ev ? (self * c - part * s) : (part * s + self * c);
                hb[(row >> 5) * 1024 + dpl + (row & 31) * 8] = f2bf(res);
            }
        }
    } else if (MODE == 0) {              // V -> VT2: chunk-tiled (dt,key-octet) planes
#pragma unroll
        for (int i = 0; i < 2; ++i)
#pragma unroll
        for (int j = 0; j < 2; ++j) {
            const int n = (nb & 7) * 128 + wc * 64 + j * 32 + ql;   // global col 0..1023
            const int head = n >> 6, d = n & 63;
            const int dt = d >> 5, dl = d & 31;
            u16* tb = VT + (size_t)head * 131072;                   // 64 chunks x 2048 u16
#pragma unroll
            for (int q = 0; q < 4; ++q) {
                const int row = row0 + wr * 64 + i * 32 + 4 * hi + 8 * q;  // key, 4 consecutive
                const int idx = (row >> 5) * 2048 + (dt * 4 + q) * 256 + dl * 8 + 4 * hi;
                u16x4 res;
                res.x = f2bf(accA[i][j][4 * q + 0]);
                res.y = f2bf(accA[i][j][4 * q + 1]);
                res.z = f2bf(accA[i][j][4 * q + 2]);
                res.w = f2bf(accA[i][j][4 * q + 3]);
                *(u16x4*)&tb[idx] = res;
            }
        }
    } else {
#pragma unroll
        for (int i = 0; i < 2; ++i)
#pragma unroll
        for (int j = 0; j < 2; ++j) {
            const int gcol = col0B + wc * 64 + j * 32 + ql;
#pragma unroll
            for (int r = 0; r < 16; ++r) {
                const int row = row0 + wr * 64 + i * 32 + 4 * hi + (r & 3) + 8 * (r >> 2);
                Of[(size_t)row * D + gcol] = accA[i][j][r];
            }
        }
    }
}

// ---------------- MFMA differential flash attention, T15 software pipeline ----------------
// Body j: prefetch j+1; QK_j (MFMA); PV_{j-1} (MFMA, independent); SM_j (TRANS/VALU,
// overlaps PV on the other pipe). V triple-buffered (set = c mod 3) so V_{j-1} stays live;
// K double-buffered; P persistent (pC). 15-body loop fully unrolled -> static set indices.
__global__ __launch_bounds__(512, 2)
void attn_mfma(const u16* __restrict__ Qb, const u16* __restrict__ Kb2,
               const u16* __restrict__ Vt2, const float* __restrict__ lamPtr,
               const float* __restrict__ g, u16* __restrict__ AO) {
    const int bid  = blockIdx.x;
    const int h    = (bid & 7) * 2 + ((bid >> 3) >> 5);   // head-affinity: XCD k owns heads {2k,2k+1}
    const int bx   = (bid >> 3) & 31;
    const int tid  = threadIdx.x;
    const int wave = tid >> 6;
    const int lane = tid & 63;
    const int hi   = lane >> 5;
    const int ql   = lane & 31;
    const int t    = wave >> 2;          // q-tile in block (0..1)
    const int wv   = wave & 3;           // kv-quarter (0..3)
    const int q0   = (bx * 2 + t) * 32;
    const int cbase = wv * 16;           // 16 chunks of 32 keys each

    __shared__ float CMB[2][64][66];     // 33.8 KB merge buffer

    const u16* qp1 = Qb + ((size_t)(2 * h) * S + q0 + ql) * HD + 8 * hi;
    const u16* qp2 = qp1 + (size_t)S * HD;
    bfrag qf1[2], qf2[2];
    qf1[0] = *(const bfrag*)(qp1);      qf1[1] = *(const bfrag*)(qp1 + 16);
    qf2[0] = *(const bfrag*)(qp2);      qf2[1] = *(const bfrag*)(qp2 + 16);

    const u16* k1g = Kb2 + (size_t)(2 * h) * 65536;      // + c*1024
    const u16* k2g = k1g + 65536;
    const u16* vg  = Vt2 + (size_t)h * 131072;           // + c*2048
    const int kro  = ql * 8;                             // lane offset within a plane

    const f16acc ZR = fillv(0.f);
    uint4v ou; ou[0] = ou[1] = ou[2] = ou[3] = 0x3F803F80u;   // bf16 1.0 pairs
    const bfrag ONES = __builtin_bit_cast(bfrag, ou);

    f16acc acc1[2], acc2[2];
    acc1[0] = fillv(0.f); acc1[1] = fillv(0.f);
    acc2[0] = fillv(0.f); acc2[1] = fillv(0.f);
    float l1 = 0.f, l2 = 0.f;

    bfrag K1s[2][2], K2s[2][2];          // K double-buffer [set][frag]
    bfrag Vs[3][2][2];                   // V triple-buffer [set][s][dt]
    bfrag pC1[2], pC2[2];                // persistent P fragments

    auto loadK = [&](int set, int c) {
        const u16* k1c = k1g + (size_t)c * 1024;
        const u16* k2c = k2g + (size_t)c * 1024;
#pragma unroll
        for (int s = 0; s < 2; ++s) {
            K1s[set][s] = *(const bfrag*)(k1c + (2 * s + hi) * 256 + kro);
            K2s[set][s] = *(const bfrag*)(k2c + (2 * s + hi) * 256 + kro);
        }
    };
    auto loadV = [&](int set, int c) {
        const u16* vvc = vg + (size_t)c * 2048;
#pragma unroll
        for (int s = 0; s < 2; ++s)
#pragma unroll
            for (int dt = 0; dt < 2; ++dt)
                Vs[set][s][dt] = *(const bfrag*)(vvc + (dt * 4 + 2 * s + hi) * 256 + kro);
    };
    auto doSM = [&](f16acc& s1, f16acc& s2) {     // exp2 + cvt + permlane -> pC
#pragma unroll
        for (int r = 0; r < 16; ++r) {
            s1[r] = exp2_raw(s1[r]);
            s2[r] = exp2_raw(s2[r]);
        }
        u32 w1[8], w2[8];
#pragma unroll
        for (int j = 0; j < 8; ++j) {
            asm("v_cvt_pk_bf16_f32 %0, %1, %2" : "=v"(w1[j]) : "v"(s1[2 * j]), "v"(s1[2 * j + 1]));
            asm("v_cvt_pk_bf16_f32 %0, %1, %2" : "=v"(w2[j]) : "v"(s2[2 * j]), "v"(s2[2 * j + 1]));
        }
        asm("v_permlane32_swap_b32 %0, %1" : "+v"(w1[0]), "+v"(w1[2]));
        asm("v_permlane32_swap_b32 %0, %1" : "+v"(w1[1]), "+v"(w1[3]));
        asm("v_permlane32_swap_b32 %0, %1" : "+v"(w1[4]), "+v"(w1[6]));
        asm("v_permlane32_swap_b32 %0, %1" : "+v"(w1[5]), "+v"(w1[7]));
        asm("v_permlane32_swap_b32 %0, %1" : "+v"(w2[0]), "+v"(w2[2]));
        asm("v_permlane32_swap_b32 %0, %1" : "+v"(w2[1]), "+v"(w2[3]));
        asm("v_permlane32_swap_b32 %0, %1" : "+v"(w2[4]), "+v"(w2[6]));
        asm("v_permlane32_swap_b32 %0, %1" : "+v"(w2[5]), "+v"(w2[7]));
        uint4v u;
        u[0] = w1[0]; u[1] = w1[1]; u[2] = w1[2]; u[3] = w1[3];
        pC1[0] = __builtin_bit_cast(bfrag, u);
        u[0] = w1[4]; u[1] = w1[5]; u[2] = w1[6]; u[3] = w1[7];
        pC1[1] = __builtin_bit_cast(bfrag, u);
        u[0] = w2[0]; u[1] = w2[1]; u[2] = w2[2]; u[3] = w2[3];
        pC2[0] = __builtin_bit_cast(bfrag, u);
        u[0] = w2[4]; u[1] = w2[5]; u[2] = w2[6]; u[3] = w2[7];
        pC2[1] = __builtin_bit_cast(bfrag, u);
    };
    auto doPV = [&](int vset) {                    // PV + l-sums of the PREVIOUS chunk
        __builtin_amdgcn_s_setprio(1);
        acc1[0] = MFMA(Vs[vset][0][0], pC1[0], acc1[0]);
        acc1[0] = MFMA(Vs[vset][1][0], pC1[1], acc1[0]);
        acc1[1] = MFMA(Vs[vset][0][1], pC1[0], acc1[1]);
        acc1[1] = MFMA(Vs[vset][1][1], pC1[1], acc1[1]);
        acc2[0] = MFMA(Vs[vset][0][0], pC2[0], acc2[0]);
        acc2[0] = MFMA(Vs[vset][1][0], pC2[1], acc2[0]);
        acc2[1] = MFMA(Vs[vset][0][1], pC2[0], acc2[1]);
        acc2[1] = MFMA(Vs[vset][1][1], pC2[1], acc2[1]);
        f16acc t1 = MFMA(ONES, pC1[0], ZR);  t1 = MFMA(ONES, pC1[1], t1);
        f16acc t2 = MFMA(ONES, pC2[0], ZR);  t2 = MFMA(ONES, pC2[1], t2);
        __builtin_amdgcn_s_setprio(0);
        l1 += t1[0];
        l2 += t2[0];
    };

    // ---- prologue: load chunks 0,1; process chunk 0 (QK + SM only) ----
    loadK(0, cbase);  loadV(0, cbase);
    loadK(1, cbase + 1);  loadV(1, cbase + 1);
    {
        __builtin_amdgcn_s_setprio(1);
        f16acc s1 = MFMA(K1s[0][0], qf1[0], ZR);  s1 = MFMA(K1s[0][1], qf1[1], s1);
        f16acc s2 = MFMA(K2s[0][0], qf2[0], ZR);  s2 = MFMA(K2s[0][1], qf2[1], s2);
        __builtin_amdgcn_s_setprio(0);
        doSM(s1, s2);
    }

    // ---- main: bodies j = 1..15 (fully unrolled -> static buffer indices) ----
#pragma unroll
    for (int j = 1; j <= 15; ++j) {
        const int cs = j & 1;                     // K set holding chunk j
        const int ns = (j + 1) & 1;               // K set to fill with chunk j+1
        const int vp = (j - 1) % 3;               // V set of chunk j-1 (for PV)
        const int vn = (j + 1) % 3;               // V set to fill with chunk j+1
        const int cn = (j < 15) ? cbase + j + 1 : cbase + 15;
        loadK(ns, cn);  loadV(vn, cn);

        __builtin_amdgcn_s_setprio(1);
        f16acc s1 = MFMA(K1s[cs][0], qf1[0], ZR);  s1 = MFMA(K1s[cs][1], qf1[1], s1);
        f16acc s2 = MFMA(K2s[cs][0], qf2[0], ZR);  s2 = MFMA(K2s[cs][1], qf2[1], s2);
        __builtin_amdgcn_s_setprio(0);

        doPV(vp);          // chunk j-1 on MFMA pipe ...
        doSM(s1, s2);      // ... overlaps chunk j softmax on TRANS/VALU
    }
    doPV(15 % 3);          // final PV (chunk 15; V in set 0)

    // ---- merge the 4 kv-quarters: pure addition ----
#pragma unroll 1
    for (int p = 1; p < 4; ++p) {
        if (wv == p) {
            float* c0 = &CMB[t][lane][0];
#pragma unroll
            for (int dt = 0; dt < 2; ++dt)
#pragma unroll
                for (int r = 0; r < 16; ++r) {
                    c0[dt * 16 + r]      = acc1[dt][r];
                    c0[32 + dt * 16 + r] = acc2[dt][r];
                }
            c0[64] = l1; c0[65] = l2;
        }
        __syncthreads();
        if (wv == 0) {
            const float* c0 = &CMB[t][lane][0];
#pragma unroll
            for (int dt = 0; dt < 2; ++dt)
#pragma unroll
                for (int r = 0; r < 16; ++r) {
                    acc1[dt][r] += c0[dt * 16 + r];
                    acc2[dt][r] += c0[32 + dt * 16 + r];
                }
            l1 += c0[64]; l2 += c0[65];
        }
        __syncthreads();
    }

    if (wv == 0) {
        const float lam = *lamPtr;
        const float inv1 = 1.0f / l1, inv2 = 1.0f / l2;
        float o_[2][16];
        float ss = 0.f;
#pragma unroll
        for (int dt = 0; dt < 2; ++dt)
#pragma unroll
            for (int r = 0; r < 16; ++r) {
                float o = acc1[dt][r] * inv1 - lam * (acc2[dt][r] * inv2);
                o_[dt][r] = o;
                ss += o * o;
            }
        ss += __shfl_xor(ss, 32);
        const float rs = rsqrtf(ss * (1.0f / 64.0f) + 1e-5f);

        u16* aorow = AO + (size_t)(q0 + ql) * D + h * 64;
#pragma unroll
        for (int dt = 0; dt < 2; ++dt)
#pragma unroll
            for (int G = 0; G < 4; ++G) {
                const int dbase = dt * 32 + G * 8 + hi * 4;
                const float4 gv = *(const float4*)&g[dbase];
                u16x4 res;
                res.x = f2bf(o_[dt][4 * G + 0] * rs * gv.x * ONE_MINUS_LI);
                res.y = f2bf(o_[dt][4 * G + 1] * rs * gv.y * ONE_MINUS_LI);
                res.z = f2bf(o_[dt][4 * G + 2] * rs * gv.z * ONE_MINUS_LI);
                res.w = f2bf(o_[dt][4 * G + 3] * rs * gv.w * ONE_MINUS_LI);
                *(u16x4*)&aorow[dbase] = res;
            }
    }
}

// ---------------- launch ----------------
extern "C" void kernel_launch(void* const* d_in, const int* in_sizes, int n_in,
                              void* d_out, int out_size, void* d_ws, size_t ws_size,
                              hipStream_t stream) {
    const float* x   = (const float*)d_in[0];
    const float* Wq  = (const float*)d_in[1];
    const float* Wk  = (const float*)d_in[2];
    const float* Wv  = (const float*)d_in[3];
    const float* Wo  = (const float*)d_in[4];
    const float* lq1 = (const float*)d_in[5];
    const float* lk1 = (const float*)d_in[6];
    const float* lq2 = (const float*)d_in[7];
    const float* lk2 = (const float*)d_in[8];
    const float* g   = (const float*)d_in[9];
    float* out = (float*)d_out;

    char* ws = (char*)d_ws;
    float* cosT = (float*)(ws);                                // 128 KB
    float* sinT = (float*)(ws + 131072);                       // 128 KB
    float* lam  = (float*)(ws + 262144);                       // 256 B
    char*  b    = ws + 262400;
    u16*   Qb   = (u16*)(b);                                   // 4 MB
    u16*   Kb2  = (u16*)(b + 4194304);                         // 4 MB (chunk-tiled planes)
    u16*   VT   = (u16*)(b + 8388608);                         // 4 MB (chunk-tiled planes)
    u16*   AO   = (u16*)(b + 12582912);                        // 4 MB (bf16)
    u16*   xb   = (u16*)(b + 16777216);                        // 4 MB
    u16*   WqT  = (u16*)(b + 20971520);                        // 2 MB
    u16*   WkT  = (u16*)(b + 23068672);                        // 2 MB
    u16*   WvT  = (u16*)(b + 25165824);                        // 2 MB
    u16*   WoT  = (u16*)(b + 27262976);                        // 2 MB

    prep_kernel<<<128, 256, 0, stream>>>(lq1, lk1, lq2, lk2, cosT, sinT, lam);
    convert_kernel<<<dim3(2048, 5), 256, 0, stream>>>(x, Wq, Wk, Wv, Wo,
                                                      xb, WqT, WkT, WvT, WoT);

    mm_kernel<0><<<dim3(24, 16), 256, 0, stream>>>(xb, WqT, WkT, WvT, cosT, sinT,
                                                   Qb, Kb2, VT, nullptr);

    attn_mfma<<<512, 512, 0, stream>>>(Qb, Kb2, VT, lam, g, AO);

    mm_kernel<1><<<dim3(8, 16), 256, 0, stream>>>(AO, WoT, nullptr, nullptr, cosT, sinT,
                                                  nullptr, nullptr, nullptr, out);
}

// Round 19
// 101.976 us; speedup vs baseline: 1.1213x; 1.1213x over previous
//
#include <hip/hip_runtime.h>
#include <math.h>

#define S 2048
#define D 1024
#define NH 16
#define HD 32
#define HD2 64

static constexpr float SCALE_Q_EXP2  = 0.17677669529663687f * 1.4426950408889634f; // *log2(e)
static constexpr float LAMBDA_INIT_F = 0.78360576653162450f;   // 0.8 - 0.6*exp(-3.6)
static constexpr float ONE_MINUS_LI  = 0.21639423346837553f;

typedef unsigned short u16;
typedef unsigned int   u32;
typedef __attribute__((ext_vector_type(4)))  unsigned short u16x4;
typedef __attribute__((ext_vector_type(8)))  short          bfrag;   // 8 bf16 = 4 VGPR
typedef __attribute__((ext_vector_type(16))) float          f16acc;  // MFMA 32x32 accumulator
typedef __attribute__((ext_vector_type(4)))  unsigned int   uint4v;

__device__ __forceinline__ u16 f2bf(float f) {                 // RNE f32->bf16
    u32 u = __builtin_bit_cast(u32, f);
    return (u16)((u + 0x7FFFu + ((u >> 16) & 1u)) >> 16);
}
__device__ __forceinline__ f16acc fillv(float v) {
    f16acc z;
#pragma unroll
    for (int i = 0; i < 16; ++i) z[i] = v;
    return z;
}
// single-instruction exp2, hazard-safe via builtin (round 14 verified)
__device__ __forceinline__ float exp2_raw(float x) {
#if __has_builtin(__builtin_amdgcn_exp2f)
    return __builtin_amdgcn_exp2f(x);
#else
    float r;
    asm volatile("v_exp_f32 %0, %1\n\ts_nop 1" : "=v"(r) : "v"(x));
    return r;
#endif
}
#define MFMA(a, b, c) __builtin_amdgcn_mfma_f32_32x32x16_bf16(a, b, c, 0, 0, 0)

__device__ __forceinline__ void gload16(const u16* src, u16* lds) {
    __builtin_amdgcn_global_load_lds((const __attribute__((address_space(1))) void*)src,
                                     (__attribute__((address_space(3))) void*)lds, 16, 0, 0);
}

// ---------------- convert (+fused prep): x -> bf16; W -> bf16 transposed; trig tables ----------------
__global__ __launch_bounds__(256)
void convert_kernel(const float* __restrict__ x,  const float* __restrict__ Wq,
                    const float* __restrict__ Wk, const float* __restrict__ Wv,
                    const float* __restrict__ Wo,
                    const float* __restrict__ lq1, const float* __restrict__ lk1,
                    const float* __restrict__ lq2, const float* __restrict__ lk2,
                    u16* __restrict__ xb,  u16* __restrict__ WqT, u16* __restrict__ WkT,
                    u16* __restrict__ WvT, u16* __restrict__ WoT,
                    float* __restrict__ cosT, float* __restrict__ sinT,
                    float* __restrict__ lamOut) {
    const int z = blockIdx.y;
    if (z == 0) {
        const int i = blockIdx.x * 256 + threadIdx.x;
        const float4 v = *(const float4*)&x[(size_t)i * 4];
        u16x4 r; r.x = f2bf(v.x); r.y = f2bf(v.y); r.z = f2bf(v.z); r.w = f2bf(v.w);
        *(u16x4*)&xb[(size_t)i * 4] = r;
        return;
    }
    if (z == 5) {   // fused prep: trig tables (f32-bit-exact numpy pipeline) + lambda
        const int idx = blockIdx.x * 256 + threadIdx.x;
        if (idx < S * 16) {
            int p = idx >> 4;
            int m = idx & 15;
            const double base = (double)1.0e-4f;
            float pf   = (float)pow(base, (double)m * (1.0 / 16.0));
            float freq = 1.0f / pf;
            float angf = (float)p * freq;
            double a = (double)angf;
            cosT[idx] = (float)cos(a);
            sinT[idx] = (float)sin(a);
        }
        if (blockIdx.x == 0 && threadIdx.x == 0) {
            float s1 = 0.f, s2 = 0.f;
            for (int i = 0; i < HD; ++i) {
                s1 += lq1[i] * lk1[i];
                s2 += lq2[i] * lk2[i];
            }
            *lamOut = expf(s1) - expf(s2) + LAMBDA_INIT_F;
        }
        return;
    }
    const int b = blockIdx.x;
    if (b >= 256) return;
    __shared__ u16 Ts[64][66];
    const float* W = (z == 1) ? Wq : (z == 2) ? Wk : (z == 3) ? Wv : Wo;
    u16* T = (z == 1) ? WqT : (z == 2) ? WkT : (z == 3) ? WvT : WoT;
    const int k0 = (b >> 4) * 64, n0 = (b & 15) * 64;
    const int rg = threadIdx.x >> 4, cc = (threadIdx.x & 15) * 4;
#pragma unroll
    for (int i = 0; i < 4; ++i) {
        const int r = rg * 4 + i;
        const float4 v = *(const float4*)&W[(size_t)(k0 + r) * D + n0 + cc];
        Ts[r][cc + 0] = f2bf(v.x); Ts[r][cc + 1] = f2bf(v.y);
        Ts[r][cc + 2] = f2bf(v.z); Ts[r][cc + 3] = f2bf(v.w);
    }
    __syncthreads();
#pragma unroll
    for (int i = 0; i < 4; ++i) {
        const int rn = rg * 4 + i;
        u16x4 res;
        res.x = Ts[cc + 0][rn]; res.y = Ts[cc + 1][rn];
        res.z = Ts[cc + 2][rn]; res.w = Ts[cc + 3][rn];
        *(u16x4*)&T[(size_t)(n0 + rn) * D + k0 + cc] = res;
    }
}

// ---------------- bf16 MFMA GEMM, 128x128 tile, BK=32, 4 waves (m97 structure) ----------------
// MODE 0: Q -> Qb row layout (RoPE+scale into exp2 domain);
//         K -> Kb2 [h2][64 chunks][4 dim-octet planes][32 key][8 u16]  (stride 1024/chunk);
//         V -> VT2 [h][64 chunks][8 (dt,key-octet) planes][32 d][8 u16] (stride 2048/chunk).
// MODE 0 uses a 1D grid with a bijective XCD swizzle (384 blocks, 48/XCD, grouped by nb
// so each XCD's B-panel working set is 0.75 MB -> L2-resident).
template<int MODE>
__global__ __launch_bounds__(256)
void mm_kernel(const u16* __restrict__ Ab, const u16* __restrict__ B0,
               const u16* __restrict__ B1, const u16* __restrict__ B2,
               const float* __restrict__ cosT, const float* __restrict__ sinT,
               u16* __restrict__ Qb, u16* __restrict__ Kb2, u16* __restrict__ VT,
               float* __restrict__ Of) {
    __shared__ u16 As[128 * 32];
    __shared__ u16 Bs[128 * 32];

    int nb, row0;
    if (MODE == 0) {
        // bijective XCD swizzle: lid -> (xcd = lid%8) owns 48 consecutive work items,
        // ordered nb-major (3 nb values x 16 rows per XCD).
        const int lid = blockIdx.x;              // 0..383
        const int xcd = lid & 7;
        const int pos = lid >> 3;                // 0..47
        const int nw  = xcd * 48 + pos;
        nb   = nw >> 4;                          // 0..23
        row0 = (nw & 15) * 128;
    } else {
        nb   = blockIdx.x;
        row0 = blockIdx.y * 128;
    }
    const int tid  = threadIdx.x;
    const int wave = tid >> 6;
    const int lane = tid & 63;
    const int ql   = lane & 31;
    const int hi   = lane >> 5;
    const int wr   = wave >> 1;
    const int wc   = wave & 1;

    const u16* Bt;
    int col0B;
    if (MODE == 0) {
        Bt = (nb < 8) ? B0 : (nb < 16) ? B1 : B2;
        col0B = (nb & 7) * 128;
    } else {
        Bt = B0;
        col0B = nb * 128;
    }

    const int rIn  = lane >> 2;
    const int kof  = 8 * (lane & 3);
    const size_t aRow0 = (size_t)(row0 + 16 * wave       + rIn) * D + kof;
    const size_t aRow1 = (size_t)(row0 + 16 * (wave + 4) + rIn) * D + kof;
    const size_t bRow0 = (size_t)(col0B + 16 * wave       + rIn) * D + kof;
    const size_t bRow1 = (size_t)(col0B + 16 * (wave + 4) + rIn) * D + kof;
    u16* ldsA0 = &As[512 * wave + 8 * lane];
    u16* ldsA1 = &As[512 * (wave + 4) + 8 * lane];
    u16* ldsB0 = &Bs[512 * wave + 8 * lane];
    u16* ldsB1 = &Bs[512 * (wave + 4) + 8 * lane];

    const int aoff = (wr * 64 + ql) * 32 + hi * 8;
    const int boff = (wc * 64 + ql) * 32 + hi * 8;

    f16acc acc00 = fillv(0.f), acc01 = fillv(0.f), acc10 = fillv(0.f), acc11 = fillv(0.f);

    for (int kk = 0; kk < D; kk += 32) {
        gload16(Ab + aRow0 + kk, ldsA0);
        gload16(Ab + aRow1 + kk, ldsA1);
        gload16(Bt + bRow0 + kk, ldsB0);
        gload16(Bt + bRow1 + kk, ldsB1);
        __syncthreads();
#pragma unroll
        for (int ks = 0; ks < 2; ++ks) {
            const bfrag a0 = *(const bfrag*)&As[aoff + ks * 16];
            const bfrag a1 = *(const bfrag*)&As[aoff + 32 * 32 + ks * 16];
            const bfrag b0 = *(const bfrag*)&Bs[boff + ks * 16];
            const bfrag b1 = *(const bfrag*)&Bs[boff + 32 * 32 + ks * 16];
            acc00 = MFMA(a0, b0, acc00);
            acc01 = MFMA(a0, b1, acc01);
            acc10 = MFMA(a1, b0, acc10);
            acc11 = MFMA(a1, b1, acc11);
        }
        __syncthreads();
    }

    f16acc accA[2][2];
    accA[0][0] = acc00; accA[0][1] = acc01; accA[1][0] = acc10; accA[1][1] = acc11;

    if (MODE == 0 && nb < 8) {           // Q: RoPE + scale, row layout
        const int m = ql >> 1;
        const bool ev = (ql & 1) == 0;
#pragma unroll
        for (int i = 0; i < 2; ++i)
#pragma unroll
        for (int j = 0; j < 2; ++j) {
            const int n = (nb & 7) * 128 + wc * 64 + j * 32 + ql;
            const int head = n >> 5;
            u16* hb = Qb + (size_t)head * S * HD;
#pragma unroll
            for (int r = 0; r < 16; ++r) {
                const int row = row0 + wr * 64 + i * 32 + 4 * hi + (r & 3) + 8 * (r >> 2);
                const float self = accA[i][j][r];
                const float part = __shfl_xor(self, 1);
                const float c = cosT[(row << 4) + m], s = sinT[(row << 4) + m];
                const float res = ev ? (self * c - part * s) : (part * s + self * c);
                hb[(size_t)row * HD + ql] = f2bf(res * SCALE_Q_EXP2);
            }
        }
    } else if (MODE == 0 && nb < 16) {   // K: RoPE, chunk-tiled dim-octet planes
        const int m = ql >> 1;
        const bool ev = (ql & 1) == 0;
#pragma unroll
        for (int i = 0; i < 2; ++i)
#pragma unroll
        for (int j = 0; j < 2; ++j) {
            const int n = (nb & 7) * 128 + wc * 64 + j * 32 + ql;
            const int h2 = n >> 5;
            const int d  = n & 31;
            const int dpl = (d >> 3) * 256 + (d & 7);
            u16* hb = Kb2 + (size_t)h2 * 65536;          // 64 chunks x 1024 u16
#pragma unroll
            for (int r = 0; r < 16; ++r) {
                const int row = row0 + wr * 64 + i * 32 + 4 * hi + (r & 3) + 8 * (r >> 2);
                const float self = accA[i][j][r];
                const float part = __shfl_xor(self, 1);
                const float c = cosT[(row << 4) + m], s = sinT[(row << 4) + m];
                const float res = ev ? (self * c - part * s) : (part * s + self * c);
                hb[(row >> 5) * 1024 + dpl + (row & 31) * 8] = f2bf(res);
            }
        }
    } else if (MODE == 0) {              // V -> VT2: chunk-tiled (dt,key-octet) planes
#pragma unroll
        for (int i = 0; i < 2; ++i)
#pragma unroll
        for (int j = 0; j < 2; ++j) {
            const int n = (nb & 7) * 128 + wc * 64 + j * 32 + ql;   // global col 0..1023
            const int head = n >> 6, d = n & 63;
            const int dt = d >> 5, dl = d & 31;
            u16* tb = VT + (size_t)head * 131072;                   // 64 chunks x 2048 u16
#pragma unroll
            for (int q = 0; q < 4; ++q) {
                const int row = row0 + wr * 64 + i * 32 + 4 * hi + 8 * q;  // key, 4 consecutive
                const int idx = (row >> 5) * 2048 + (dt * 4 + q) * 256 + dl * 8 + 4 * hi;
                u16x4 res;
                res.x = f2bf(accA[i][j][4 * q + 0]);
                res.y = f2bf(accA[i][j][4 * q + 1]);
                res.z = f2bf(accA[i][j][4 * q + 2]);
                res.w = f2bf(accA[i][j][4 * q + 3]);
                *(u16x4*)&tb[idx] = res;
            }
        }
    } else {
#pragma unroll
        for (int i = 0; i < 2; ++i)
#pragma unroll
        for (int j = 0; j < 2; ++j) {
            const int gcol = col0B + wc * 64 + j * 32 + ql;
#pragma unroll
            for (int r = 0; r < 16; ++r) {
                const int row = row0 + wr * 64 + i * 32 + 4 * hi + (r & 3) + 8 * (r >> 2);
                Of[(size_t)row * D + gcol] = accA[i][j][r];
            }
        }
    }
}

// ---------------- MFMA differential flash attention (R17 verbatim: best measured) ----------------
__global__ __launch_bounds__(512, 2)
void attn_mfma(const u16* __restrict__ Qb, const u16* __restrict__ Kb2,
               const u16* __restrict__ Vt2, const float* __restrict__ lamPtr,
               const float* __restrict__ g, u16* __restrict__ AO) {
    const int bid  = blockIdx.x;
    const int h    = (bid & 7) * 2 + ((bid >> 3) >> 5);   // head-affinity: XCD k owns heads {2k,2k+1}
    const int bx   = (bid >> 3) & 31;
    const int tid  = threadIdx.x;
    const int wave = tid >> 6;
    const int lane = tid & 63;
    const int hi   = lane >> 5;
    const int ql   = lane & 31;
    const int t    = wave >> 2;          // q-tile in block (0..1)
    const int wv   = wave & 3;           // kv-quarter (0..3)
    const int q0   = (bx * 2 + t) * 32;
    const int cbase = wv * 16;           // 16 chunks of 32 keys each

    __shared__ float CMB[2][64][66];     // 33.8 KB merge buffer

    const u16* qp1 = Qb + ((size_t)(2 * h) * S + q0 + ql) * HD + 8 * hi;
    const u16* qp2 = qp1 + (size_t)S * HD;
    bfrag qf1[2], qf2[2];
    qf1[0] = *(const bfrag*)(qp1);      qf1[1] = *(const bfrag*)(qp1 + 16);
    qf2[0] = *(const bfrag*)(qp2);      qf2[1] = *(const bfrag*)(qp2 + 16);

    const u16* k1g = Kb2 + (size_t)(2 * h) * 65536;      // + c*1024
    const u16* k2g = k1g + 65536;
    const u16* vg  = Vt2 + (size_t)h * 131072;           // + c*2048
    const int kro  = ql * 8;                             // lane offset within a plane

    const f16acc ZR = fillv(0.f);
    uint4v ou; ou[0] = ou[1] = ou[2] = ou[3] = 0x3F803F80u;   // bf16 1.0 pairs
    const bfrag ONES = __builtin_bit_cast(bfrag, ou);

    f16acc acc1[2], acc2[2];
    acc1[0] = fillv(0.f); acc1[1] = fillv(0.f);
    acc2[0] = fillv(0.f); acc2[1] = fillv(0.f);
    float l1 = 0.f, l2 = 0.f;

    bfrag kA1[2], kA2[2], kB1[2], kB2[2];
    bfrag vA[2][2], vB[2][2];
#pragma unroll
    for (int s = 0; s < 2; ++s) {
        kA1[s] = *(const bfrag*)(k1g + (size_t)cbase * 1024 + (2 * s + hi) * 256 + kro);
        kA2[s] = *(const bfrag*)(k2g + (size_t)cbase * 1024 + (2 * s + hi) * 256 + kro);
#pragma unroll
        for (int dt = 0; dt < 2; ++dt)
            vA[s][dt] = *(const bfrag*)(vg + (size_t)cbase * 2048 + (dt * 4 + 2 * s + hi) * 256 + kro);
    }

    auto body = [&](bfrag (&kc1)[2], bfrag (&kc2)[2], bfrag (&vc)[2][2],
                    bfrag (&kn1)[2], bfrag (&kn2)[2], bfrag (&vn)[2][2], int cn) {
        // prefetch next chunk (contiguous full-line loads)
        const u16* k1c = k1g + (size_t)cn * 1024;
        const u16* k2c = k2g + (size_t)cn * 1024;
        const u16* vvc = vg + (size_t)cn * 2048;
#pragma unroll
        for (int s = 0; s < 2; ++s) {
            kn1[s] = *(const bfrag*)(k1c + (2 * s + hi) * 256 + kro);
            kn2[s] = *(const bfrag*)(k2c + (2 * s + hi) * 256 + kro);
#pragma unroll
            for (int dt = 0; dt < 2; ++dt)
                vn[s][dt] = *(const bfrag*)(vvc + (dt * 4 + 2 * s + hi) * 256 + kro);
        }

        __builtin_amdgcn_s_setprio(1);
        f16acc s1 = MFMA(kc1[0], qf1[0], ZR);  s1 = MFMA(kc1[1], qf1[1], s1);
        f16acc s2 = MFMA(kc2[0], qf2[0], ZR);  s2 = MFMA(kc2[1], qf2[1], s2);
        __builtin_amdgcn_s_setprio(0);

#pragma unroll
        for (int r = 0; r < 16; ++r) {       // P = 2^s, single v_exp_f32 each
            s1[r] = exp2_raw(s1[r]);
            s2[r] = exp2_raw(s2[r]);
        }

        u32 w1[8], w2[8];
#pragma unroll
        for (int j = 0; j < 8; ++j) {
            asm("v_cvt_pk_bf16_f32 %0, %1, %2" : "=v"(w1[j]) : "v"(s1[2 * j]), "v"(s1[2 * j + 1]));
            asm("v_cvt_pk_bf16_f32 %0, %1, %2" : "=v"(w2[j]) : "v"(s2[2 * j]), "v"(s2[2 * j + 1]));
        }
        asm("v_permlane32_swap_b32 %0, %1" : "+v"(w1[0]), "+v"(w1[2]));
        asm("v_permlane32_swap_b32 %0, %1" : "+v"(w1[1]), "+v"(w1[3]));
        asm("v_permlane32_swap_b32 %0, %1" : "+v"(w1[4]), "+v"(w1[6]));
        asm("v_permlane32_swap_b32 %0, %1" : "+v"(w1[5]), "+v"(w1[7]));
        asm("v_permlane32_swap_b32 %0, %1" : "+v"(w2[0]), "+v"(w2[2]));
        asm("v_permlane32_swap_b32 %0, %1" : "+v"(w2[1]), "+v"(w2[3]));
        asm("v_permlane32_swap_b32 %0, %1" : "+v"(w2[4]), "+v"(w2[6]));
        asm("v_permlane32_swap_b32 %0, %1" : "+v"(w2[5]), "+v"(w2[7]));
        uint4v u;
        bfrag p1[2], p2[2];
        u[0] = w1[0]; u[1] = w1[1]; u[2] = w1[2]; u[3] = w1[3];
        p1[0] = __builtin_bit_cast(bfrag, u);
        u[0] = w1[4]; u[1] = w1[5]; u[2] = w1[6]; u[3] = w1[7];
        p1[1] = __builtin_bit_cast(bfrag, u);
        u[0] = w2[0]; u[1] = w2[1]; u[2] = w2[2]; u[3] = w2[3];
        p2[0] = __builtin_bit_cast(bfrag, u);
        u[0] = w2[4]; u[1] = w2[5]; u[2] = w2[6]; u[3] = w2[7];
        p2[1] = __builtin_bit_cast(bfrag, u);

        __builtin_amdgcn_s_setprio(1);
        acc1[0] = MFMA(vc[0][0], p1[0], acc1[0]);
        acc1[0] = MFMA(vc[1][0], p1[1], acc1[0]);
        acc1[1] = MFMA(vc[0][1], p1[0], acc1[1]);
        acc1[1] = MFMA(vc[1][1], p1[1], acc1[1]);
        acc2[0] = MFMA(vc[0][0], p2[0], acc2[0]);
        acc2[0] = MFMA(vc[1][0], p2[1], acc2[0]);
        acc2[1] = MFMA(vc[0][1], p2[0], acc2[1]);
        acc2[1] = MFMA(vc[1][1], p2[1], acc2[1]);
        f16acc t1 = MFMA(ONES, p1[0], ZR);  t1 = MFMA(ONES, p1[1], t1);
        f16acc t2 = MFMA(ONES, p2[0], ZR);  t2 = MFMA(ONES, p2[1], t2);
        __builtin_amdgcn_s_setprio(0);
        l1 += t1[0];
        l2 += t2[0];
    };

    // explicit 2x unroll ping-pong on K and V (no rotate movs)
    for (int i = 0; i < 16; i += 2) {
        const int c0 = cbase + i;
        body(kA1, kA2, vA, kB1, kB2, vB, c0 + 1);
        const int c2 = (i + 2 < 16) ? c0 + 2 : c0 + 1;
        body(kB1, kB2, vB, kA1, kA2, vA, c2);
    }

    // ---- merge the 4 kv-quarters: pure addition ----
#pragma unroll 1
    for (int p = 1; p < 4; ++p) {
        if (wv == p) {
            float* c0 = &CMB[t][lane][0];
#pragma unroll
            for (int dt = 0; dt < 2; ++dt)
#pragma unroll
                for (int r = 0; r < 16; ++r) {
                    c0[dt * 16 + r]      = acc1[dt][r];
                    c0[32 + dt * 16 + r] = acc2[dt][r];
                }
            c0[64] = l1; c0[65] = l2;
        }
        __syncthreads();
        if (wv == 0) {
            const float* c0 = &CMB[t][lane][0];
#pragma unroll
            for (int dt = 0; dt < 2; ++dt)
#pragma unroll
                for (int r = 0; r < 16; ++r) {
                    acc1[dt][r] += c0[dt * 16 + r];
                    acc2[dt][r] += c0[32 + dt * 16 + r];
                }
            l1 += c0[64]; l2 += c0[65];
        }
        __syncthreads();
    }

    if (wv == 0) {
        const float lam = *lamPtr;
        const float inv1 = 1.0f / l1, inv2 = 1.0f / l2;
        float o_[2][16];
        float ss = 0.f;
#pragma unroll
        for (int dt = 0; dt < 2; ++dt)
#pragma unroll
            for (int r = 0; r < 16; ++r) {
                float o = acc1[dt][r] * inv1 - lam * (acc2[dt][r] * inv2);
                o_[dt][r] = o;
                ss += o * o;
            }
        ss += __shfl_xor(ss, 32);
        const float rs = rsqrtf(ss * (1.0f / 64.0f) + 1e-5f);

        u16* aorow = AO + (size_t)(q0 + ql) * D + h * 64;
#pragma unroll
        for (int dt = 0; dt < 2; ++dt)
#pragma unroll
            for (int G = 0; G < 4; ++G) {
                const int dbase = dt * 32 + G * 8 + hi * 4;
                const float4 gv = *(const float4*)&g[dbase];
                u16x4 res;
                res.x = f2bf(o_[dt][4 * G + 0] * rs * gv.x * ONE_MINUS_LI);
                res.y = f2bf(o_[dt][4 * G + 1] * rs * gv.y * ONE_MINUS_LI);
                res.z = f2bf(o_[dt][4 * G + 2] * rs * gv.z * ONE_MINUS_LI);
                res.w = f2bf(o_[dt][4 * G + 3] * rs * gv.w * ONE_MINUS_LI);
                *(u16x4*)&aorow[dbase] = res;
            }
    }
}

// ---------------- launch ----------------
extern "C" void kernel_launch(void* const* d_in, const int* in_sizes, int n_in,
                              void* d_out, int out_size, void* d_ws, size_t ws_size,
                              hipStream_t stream) {
    const float* x   = (const float*)d_in[0];
    const float* Wq  = (const float*)d_in[1];
    const float* Wk  = (const float*)d_in[2];
    const float* Wv  = (const float*)d_in[3];
    const float* Wo  = (const float*)d_in[4];
    const float* lq1 = (const float*)d_in[5];
    const float* lk1 = (const float*)d_in[6];
    const float* lq2 = (const float*)d_in[7];
    const float* lk2 = (const float*)d_in[8];
    const float* g   = (const float*)d_in[9];
    float* out = (float*)d_out;

    char* ws = (char*)d_ws;
    float* cosT = (float*)(ws);                                // 128 KB
    float* sinT = (float*)(ws + 131072);                       // 128 KB
    float* lam  = (float*)(ws + 262144);                       // 256 B
    char*  b    = ws + 262400;
    u16*   Qb   = (u16*)(b);                                   // 4 MB
    u16*   Kb2  = (u16*)(b + 4194304);                         // 4 MB (chunk-tiled planes)
    u16*   VT   = (u16*)(b + 8388608);                         // 4 MB (chunk-tiled planes)
    u16*   AO   = (u16*)(b + 12582912);                        // 4 MB (bf16)
    u16*   xb   = (u16*)(b + 16777216);                        // 4 MB
    u16*   WqT  = (u16*)(b + 20971520);                        // 2 MB
    u16*   WkT  = (u16*)(b + 23068672);                        // 2 MB
    u16*   WvT  = (u16*)(b + 25165824);                        // 2 MB
    u16*   WoT  = (u16*)(b + 27262976);                        // 2 MB

    convert_kernel<<<dim3(2048, 6), 256, 0, stream>>>(x, Wq, Wk, Wv, Wo,
                                                      lq1, lk1, lq2, lk2,
                                                      xb, WqT, WkT, WvT, WoT,
                                                      cosT, sinT, lam);

    mm_kernel<0><<<384, 256, 0, stream>>>(xb, WqT, WkT, WvT, cosT, sinT,
                                          Qb, Kb2, VT, nullptr);

    attn_mfma<<<512, 512, 0, stream>>>(Qb, Kb2, VT, lam, g, AO);

    mm_kernel<1><<<dim3(8, 16), 256, 0, stream>>>(AO, WoT, nullptr, nullptr, cosT, sinT,
                                                  nullptr, nullptr, nullptr, out);
}

// Round 20
// 98.438 us; speedup vs baseline: 1.1616x; 1.0359x over previous
//
#include <hip/hip_runtime.h>
#include <math.h>

#define S 2048
#define D 1024
#define NH 16
#define HD 32
#define HD2 64

static constexpr float SCALE_Q_EXP2  = 0.17677669529663687f * 1.4426950408889634f; // *log2(e)
static constexpr float LAMBDA_INIT_F = 0.78360576653162450f;   // 0.8 - 0.6*exp(-3.6)
static constexpr float ONE_MINUS_LI  = 0.21639423346837553f;

typedef unsigned short u16;
typedef unsigned int   u32;
typedef __attribute__((ext_vector_type(4)))  unsigned short u16x4;
typedef __attribute__((ext_vector_type(8)))  short          bfrag;   // 8 bf16 = 4 VGPR
typedef __attribute__((ext_vector_type(16))) float          f16acc;  // MFMA 32x32 accumulator
typedef __attribute__((ext_vector_type(4)))  unsigned int   uint4v;

__device__ __forceinline__ u16 f2bf(float f) {                 // RNE f32->bf16
    u32 u = __builtin_bit_cast(u32, f);
    return (u16)((u + 0x7FFFu + ((u >> 16) & 1u)) >> 16);
}
__device__ __forceinline__ f16acc fillv(float v) {
    f16acc z;
#pragma unroll
    for (int i = 0; i < 16; ++i) z[i] = v;
    return z;
}
// single-instruction exp2, hazard-safe via builtin (round 14 verified)
__device__ __forceinline__ float exp2_raw(float x) {
#if __has_builtin(__builtin_amdgcn_exp2f)
    return __builtin_amdgcn_exp2f(x);
#else
    float r;
    asm volatile("v_exp_f32 %0, %1\n\ts_nop 1" : "=v"(r) : "v"(x));
    return r;
#endif
}
#define MFMA(a, b, c) __builtin_amdgcn_mfma_f32_32x32x16_bf16(a, b, c, 0, 0, 0)

__device__ __forceinline__ void gload16(const u16* src, u16* lds) {
    __builtin_amdgcn_global_load_lds((const __attribute__((address_space(1))) void*)src,
                                     (__attribute__((address_space(3))) void*)lds, 16, 0, 0);
}

// ---------------- convert (+fused prep): x -> bf16; W -> bf16 transposed; trig tables ----------------
__global__ __launch_bounds__(256)
void convert_kernel(const float* __restrict__ x,  const float* __restrict__ Wq,
                    const float* __restrict__ Wk, const float* __restrict__ Wv,
                    const float* __restrict__ Wo,
                    const float* __restrict__ lq1, const float* __restrict__ lk1,
                    const float* __restrict__ lq2, const float* __restrict__ lk2,
                    u16* __restrict__ xb,  u16* __restrict__ WqT, u16* __restrict__ WkT,
                    u16* __restrict__ WvT, u16* __restrict__ WoT,
                    float* __restrict__ cosT, float* __restrict__ sinT,
                    float* __restrict__ lamOut) {
    const int z = blockIdx.y;
    if (z == 0) {
        const int i = blockIdx.x * 256 + threadIdx.x;
        const float4 v = *(const float4*)&x[(size_t)i * 4];
        u16x4 r; r.x = f2bf(v.x); r.y = f2bf(v.y); r.z = f2bf(v.z); r.w = f2bf(v.w);
        *(u16x4*)&xb[(size_t)i * 4] = r;
        return;
    }
    if (z == 5) {   // fused prep: trig tables (f32-bit-exact numpy pipeline) + lambda
        const int idx = blockIdx.x * 256 + threadIdx.x;
        if (idx < S * 16) {
            int p = idx >> 4;
            int m = idx & 15;
            const double base = (double)1.0e-4f;
            float pf   = (float)pow(base, (double)m * (1.0 / 16.0));
            float freq = 1.0f / pf;
            float angf = (float)p * freq;
            double a = (double)angf;
            cosT[idx] = (float)cos(a);
            sinT[idx] = (float)sin(a);
        }
        if (blockIdx.x == 0 && threadIdx.x == 0) {
            float s1 = 0.f, s2 = 0.f;
            for (int i = 0; i < HD; ++i) {
                s1 += lq1[i] * lk1[i];
                s2 += lq2[i] * lk2[i];
            }
            *lamOut = expf(s1) - expf(s2) + LAMBDA_INIT_F;
        }
        return;
    }
    const int b = blockIdx.x;
    if (b >= 256) return;
    __shared__ u16 Ts[64][66];
    const float* W = (z == 1) ? Wq : (z == 2) ? Wk : (z == 3) ? Wv : Wo;
    u16* T = (z == 1) ? WqT : (z == 2) ? WkT : (z == 3) ? WvT : WoT;
    const int k0 = (b >> 4) * 64, n0 = (b & 15) * 64;
    const int rg = threadIdx.x >> 4, cc = (threadIdx.x & 15) * 4;
#pragma unroll
    for (int i = 0; i < 4; ++i) {
        const int r = rg * 4 + i;
        const float4 v = *(const float4*)&W[(size_t)(k0 + r) * D + n0 + cc];
        Ts[r][cc + 0] = f2bf(v.x); Ts[r][cc + 1] = f2bf(v.y);
        Ts[r][cc + 2] = f2bf(v.z); Ts[r][cc + 3] = f2bf(v.w);
    }
    __syncthreads();
#pragma unroll
    for (int i = 0; i < 4; ++i) {
        const int rn = rg * 4 + i;
        u16x4 res;
        res.x = Ts[cc + 0][rn]; res.y = Ts[cc + 1][rn];
        res.z = Ts[cc + 2][rn]; res.w = Ts[cc + 3][rn];
        *(u16x4*)&T[(size_t)(n0 + rn) * D + k0 + cc] = res;
    }
}

// ---------------- bf16 MFMA GEMM, 64x128 tile, BK=32, 4 waves ----------------
// Smaller M-tile for exact grid balance: mm0 = 768 blocks (3/CU, XCD-bijective swizzle),
// mm1 = 256 blocks (1/CU; linear id gives each XCD one B panel).
// Each wave owns a 32-row x 64-col strip: acc[2] (32 VGPR).
// MODE 0: Q -> Qb row layout (RoPE+scale); K -> Kb2 dim-octet planes; V -> VT2 planes.
// MODE 1: f32 row-major output.
template<int MODE>
__global__ __launch_bounds__(256)
void mm_kernel(const u16* __restrict__ Ab, const u16* __restrict__ B0,
               const u16* __restrict__ B1, const u16* __restrict__ B2,
               const float* __restrict__ cosT, const float* __restrict__ sinT,
               u16* __restrict__ Qb, u16* __restrict__ Kb2, u16* __restrict__ VT,
               float* __restrict__ Of) {
    __shared__ u16 As[64 * 32];      // 4 KB
    __shared__ u16 Bs[128 * 32];     // 8 KB

    int nb, row0;
    if (MODE == 0) {
        // bijective XCD swizzle: 768 blocks, XCD k owns 96 consecutive work items
        // (3 nb values x 32 row-tiles) -> per-XCD B working set 0.75 MB, L2-resident.
        const int lid = blockIdx.x;              // 0..767
        const int xcd = lid & 7;
        const int pos = lid >> 3;                // 0..95
        const int nw  = xcd * 96 + pos;
        nb   = nw >> 5;                          // 0..23
        row0 = (nw & 31) * 64;
    } else {
        nb   = blockIdx.x;                       // 0..7
        row0 = blockIdx.y * 64;                  // 0..31 tiles
    }
    const int tid  = threadIdx.x;
    const int wave = tid >> 6;
    const int lane = tid & 63;
    const int ql   = lane & 31;
    const int hi   = lane >> 5;
    const int wr   = wave >> 1;      // 0,1 -> 32-row half
    const int wc   = wave & 1;       // 0,1 -> 64-col half

    const u16* Bt;
    int col0B;
    if (MODE == 0) {
        Bt = (nb < 8) ? B0 : (nb < 16) ? B1 : B2;
        col0B = (nb & 7) * 128;
    } else {
        Bt = B0;
        col0B = nb * 128;
    }

    // staging: A 64x32 (1 gload/thread), B 128x32 (2 gloads/thread)
    const int rIn = tid >> 2;                    // 0..63
    const int kof = 8 * (tid & 3);
    const size_t aRow  = (size_t)(row0 + rIn) * D + kof;
    const size_t bRow0 = (size_t)(col0B + rIn) * D + kof;
    const size_t bRow1 = (size_t)(col0B + 64 + rIn) * D + kof;
    u16* ldsA  = &As[8 * tid];
    u16* ldsB0 = &Bs[8 * tid];
    u16* ldsB1 = &Bs[2048 + 8 * tid];

    const int aoff  = (wr * 32 + ql) * 32 + hi * 8;
    const int boff0 = (wc * 64 + ql) * 32 + hi * 8;
    const int boff1 = (wc * 64 + 32 + ql) * 32 + hi * 8;

    f16acc acc0 = fillv(0.f), acc1 = fillv(0.f);

    for (int kk = 0; kk < D; kk += 32) {
        gload16(Ab + aRow + kk, ldsA);
        gload16(Bt + bRow0 + kk, ldsB0);
        gload16(Bt + bRow1 + kk, ldsB1);
        __syncthreads();
#pragma unroll
        for (int ks = 0; ks < 2; ++ks) {
            const bfrag a  = *(const bfrag*)&As[aoff + ks * 16];
            const bfrag b0 = *(const bfrag*)&Bs[boff0 + ks * 16];
            const bfrag b1 = *(const bfrag*)&Bs[boff1 + ks * 16];
            acc0 = MFMA(a, b0, acc0);
            acc1 = MFMA(a, b1, acc1);
        }
        __syncthreads();
    }

    f16acc accA[2];
    accA[0] = acc0; accA[1] = acc1;

    if (MODE == 0 && nb < 8) {           // Q: RoPE + scale, row layout
        const int m = ql >> 1;
        const bool ev = (ql & 1) == 0;
#pragma unroll
        for (int j = 0; j < 2; ++j) {
            const int n = (nb & 7) * 128 + wc * 64 + j * 32 + ql;
            const int head = n >> 5;
            u16* hb = Qb + (size_t)head * S * HD;
#pragma unroll
            for (int r = 0; r < 16; ++r) {
                const int row = row0 + wr * 32 + 4 * hi + (r & 3) + 8 * (r >> 2);
                const float self = accA[j][r];
                const float part = __shfl_xor(self, 1);
                const float c = cosT[(row << 4) + m], s = sinT[(row << 4) + m];
                const float res = ev ? (self * c - part * s) : (part * s + self * c);
                hb[(size_t)row * HD + ql] = f2bf(res * SCALE_Q_EXP2);
            }
        }
    } else if (MODE == 0 && nb < 16) {   // K: RoPE, chunk-tiled dim-octet planes
        const int m = ql >> 1;
        const bool ev = (ql & 1) == 0;
#pragma unroll
        for (int j = 0; j < 2; ++j) {
            const int n = (nb & 7) * 128 + wc * 64 + j * 32 + ql;
            const int h2 = n >> 5;
            const int d  = n & 31;
            const int dpl = (d >> 3) * 256 + (d & 7);
            u16* hb = Kb2 + (size_t)h2 * 65536;          // 64 chunks x 1024 u16
#pragma unroll
            for (int r = 0; r < 16; ++r) {
                const int row = row0 + wr * 32 + 4 * hi + (r & 3) + 8 * (r >> 2);
                const float self = accA[j][r];
                const float part = __shfl_xor(self, 1);
                const float c = cosT[(row << 4) + m], s = sinT[(row << 4) + m];
                const float res = ev ? (self * c - part * s) : (part * s + self * c);
                hb[(row >> 5) * 1024 + dpl + (row & 31) * 8] = f2bf(res);
            }
        }
    } else if (MODE == 0) {              // V -> VT2: chunk-tiled (dt,key-octet) planes
#pragma unroll
        for (int j = 0; j < 2; ++j) {
            const int n = (nb & 7) * 128 + wc * 64 + j * 32 + ql;   // global col 0..1023
            const int head = n >> 6, d = n & 63;
            const int dt = d >> 5, dl = d & 31;
            u16* tb = VT + (size_t)head * 131072;                   // 64 chunks x 2048 u16
#pragma unroll
            for (int q = 0; q < 4; ++q) {
                const int row = row0 + wr * 32 + 4 * hi + 8 * q;    // key, 4 consecutive
                const int idx = (row >> 5) * 2048 + (dt * 4 + q) * 256 + dl * 8 + 4 * hi;
                u16x4 res;
                res.x = f2bf(accA[j][4 * q + 0]);
                res.y = f2bf(accA[j][4 * q + 1]);
                res.z = f2bf(accA[j][4 * q + 2]);
                res.w = f2bf(accA[j][4 * q + 3]);
                *(u16x4*)&tb[idx] = res;
            }
        }
    } else {
#pragma unroll
        for (int j = 0; j < 2; ++j) {
            const int gcol = col0B + wc * 64 + j * 32 + ql;
#pragma unroll
            for (int r = 0; r < 16; ++r) {
                const int row = row0 + wr * 32 + 4 * hi + (r & 3) + 8 * (r >> 2);
                Of[(size_t)row * D + gcol] = accA[j][r];
            }
        }
    }
}

// ---------------- MFMA differential flash attention (R17/R19 verbatim: best measured) ----------------
__global__ __launch_bounds__(512, 2)
void attn_mfma(const u16* __restrict__ Qb, const u16* __restrict__ Kb2,
               const u16* __restrict__ Vt2, const float* __restrict__ lamPtr,
               const float* __restrict__ g, u16* __restrict__ AO) {
    const int bid  = blockIdx.x;
    const int h    = (bid & 7) * 2 + ((bid >> 3) >> 5);   // head-affinity: XCD k owns heads {2k,2k+1}
    const int bx   = (bid >> 3) & 31;
    const int tid  = threadIdx.x;
    const int wave = tid >> 6;
    const int lane = tid & 63;
    const int hi   = lane >> 5;
    const int ql   = lane & 31;
    const int t    = wave >> 2;          // q-tile in block (0..1)
    const int wv   = wave & 3;           // kv-quarter (0..3)
    const int q0   = (bx * 2 + t) * 32;
    const int cbase = wv * 16;           // 16 chunks of 32 keys each

    __shared__ float CMB[2][64][66];     // 33.8 KB merge buffer

    const u16* qp1 = Qb + ((size_t)(2 * h) * S + q0 + ql) * HD + 8 * hi;
    const u16* qp2 = qp1 + (size_t)S * HD;
    bfrag qf1[2], qf2[2];
    qf1[0] = *(const bfrag*)(qp1);      qf1[1] = *(const bfrag*)(qp1 + 16);
    qf2[0] = *(const bfrag*)(qp2);      qf2[1] = *(const bfrag*)(qp2 + 16);

    const u16* k1g = Kb2 + (size_t)(2 * h) * 65536;      // + c*1024
    const u16* k2g = k1g + 65536;
    const u16* vg  = Vt2 + (size_t)h * 131072;           // + c*2048
    const int kro  = ql * 8;                             // lane offset within a plane

    const f16acc ZR = fillv(0.f);
    uint4v ou; ou[0] = ou[1] = ou[2] = ou[3] = 0x3F803F80u;   // bf16 1.0 pairs
    const bfrag ONES = __builtin_bit_cast(bfrag, ou);

    f16acc acc1[2], acc2[2];
    acc1[0] = fillv(0.f); acc1[1] = fillv(0.f);
    acc2[0] = fillv(0.f); acc2[1] = fillv(0.f);
    float l1 = 0.f, l2 = 0.f;

    bfrag kA1[2], kA2[2], kB1[2], kB2[2];
    bfrag vA[2][2], vB[2][2];
#pragma unroll
    for (int s = 0; s < 2; ++s) {
        kA1[s] = *(const bfrag*)(k1g + (size_t)cbase * 1024 + (2 * s + hi) * 256 + kro);
        kA2[s] = *(const bfrag*)(k2g + (size_t)cbase * 1024 + (2 * s + hi) * 256 + kro);
#pragma unroll
        for (int dt = 0; dt < 2; ++dt)
            vA[s][dt] = *(const bfrag*)(vg + (size_t)cbase * 2048 + (dt * 4 + 2 * s + hi) * 256 + kro);
    }

    auto body = [&](bfrag (&kc1)[2], bfrag (&kc2)[2], bfrag (&vc)[2][2],
                    bfrag (&kn1)[2], bfrag (&kn2)[2], bfrag (&vn)[2][2], int cn) {
        // prefetch next chunk (contiguous full-line loads)
        const u16* k1c = k1g + (size_t)cn * 1024;
        const u16* k2c = k2g + (size_t)cn * 1024;
        const u16* vvc = vg + (size_t)cn * 2048;
#pragma unroll
        for (int s = 0; s < 2; ++s) {
            kn1[s] = *(const bfrag*)(k1c + (2 * s + hi) * 256 + kro);
            kn2[s] = *(const bfrag*)(k2c + (2 * s + hi) * 256 + kro);
#pragma unroll
            for (int dt = 0; dt < 2; ++dt)
                vn[s][dt] = *(const bfrag*)(vvc + (dt * 4 + 2 * s + hi) * 256 + kro);
        }

        __builtin_amdgcn_s_setprio(1);
        f16acc s1 = MFMA(kc1[0], qf1[0], ZR);  s1 = MFMA(kc1[1], qf1[1], s1);
        f16acc s2 = MFMA(kc2[0], qf2[0], ZR);  s2 = MFMA(kc2[1], qf2[1], s2);
        __builtin_amdgcn_s_setprio(0);

#pragma unroll
        for (int r = 0; r < 16; ++r) {       // P = 2^s, single v_exp_f32 each
            s1[r] = exp2_raw(s1[r]);
            s2[r] = exp2_raw(s2[r]);
        }

        u32 w1[8], w2[8];
#pragma unroll
        for (int j = 0; j < 8; ++j) {
            asm("v_cvt_pk_bf16_f32 %0, %1, %2" : "=v"(w1[j]) : "v"(s1[2 * j]), "v"(s1[2 * j + 1]));
            asm("v_cvt_pk_bf16_f32 %0, %1, %2" : "=v"(w2[j]) : "v"(s2[2 * j]), "v"(s2[2 * j + 1]));
        }
        asm("v_permlane32_swap_b32 %0, %1" : "+v"(w1[0]), "+v"(w1[2]));
        asm("v_permlane32_swap_b32 %0, %1" : "+v"(w1[1]), "+v"(w1[3]));
        asm("v_permlane32_swap_b32 %0, %1" : "+v"(w1[4]), "+v"(w1[6]));
        asm("v_permlane32_swap_b32 %0, %1" : "+v"(w1[5]), "+v"(w1[7]));
        asm("v_permlane32_swap_b32 %0, %1" : "+v"(w2[0]), "+v"(w2[2]));
        asm("v_permlane32_swap_b32 %0, %1" : "+v"(w2[1]), "+v"(w2[3]));
        asm("v_permlane32_swap_b32 %0, %1" : "+v"(w2[4]), "+v"(w2[6]));
        asm("v_permlane32_swap_b32 %0, %1" : "+v"(w2[5]), "+v"(w2[7]));
        uint4v u;
        bfrag p1[2], p2[2];
        u[0] = w1[0]; u[1] = w1[1]; u[2] = w1[2]; u[3] = w1[3];
        p1[0] = __builtin_bit_cast(bfrag, u);
        u[0] = w1[4]; u[1] = w1[5]; u[2] = w1[6]; u[3] = w1[7];
        p1[1] = __builtin_bit_cast(bfrag, u);
        u[0] = w2[0]; u[1] = w2[1]; u[2] = w2[2]; u[3] = w2[3];
        p2[0] = __builtin_bit_cast(bfrag, u);
        u[0] = w2[4]; u[1] = w2[5]; u[2] = w2[6]; u[3] = w2[7];
        p2[1] = __builtin_bit_cast(bfrag, u);

        __builtin_amdgcn_s_setprio(1);
        acc1[0] = MFMA(vc[0][0], p1[0], acc1[0]);
        acc1[0] = MFMA(vc[1][0], p1[1], acc1[0]);
        acc1[1] = MFMA(vc[0][1], p1[0], acc1[1]);
        acc1[1] = MFMA(vc[1][1], p1[1], acc1[1]);
        acc2[0] = MFMA(vc[0][0], p2[0], acc2[0]);
        acc2[0] = MFMA(vc[1][0], p2[1], acc2[0]);
        acc2[1] = MFMA(vc[0][1], p2[0], acc2[1]);
        acc2[1] = MFMA(vc[1][1], p2[1], acc2[1]);
        f16acc t1 = MFMA(ONES, p1[0], ZR);  t1 = MFMA(ONES, p1[1], t1);
        f16acc t2 = MFMA(ONES, p2[0], ZR);  t2 = MFMA(ONES, p2[1], t2);
        __builtin_amdgcn_s_setprio(0);
        l1 += t1[0];
        l2 += t2[0];
    };

    // explicit 2x unroll ping-pong on K and V (no rotate movs)
    for (int i = 0; i < 16; i += 2) {
        const int c0 = cbase + i;
        body(kA1, kA2, vA, kB1, kB2, vB, c0 + 1);
        const int c2 = (i + 2 < 16) ? c0 + 2 : c0 + 1;
        body(kB1, kB2, vB, kA1, kA2, vA, c2);
    }

    // ---- merge the 4 kv-quarters: pure addition ----
#pragma unroll 1
    for (int p = 1; p < 4; ++p) {
        if (wv == p) {
            float* c0 = &CMB[t][lane][0];
#pragma unroll
            for (int dt = 0; dt < 2; ++dt)
#pragma unroll
                for (int r = 0; r < 16; ++r) {
                    c0[dt * 16 + r]      = acc1[dt][r];
                    c0[32 + dt * 16 + r] = acc2[dt][r];
                }
            c0[64] = l1; c0[65] = l2;
        }
        __syncthreads();
        if (wv == 0) {
            const float* c0 = &CMB[t][lane][0];
#pragma unroll
            for (int dt = 0; dt < 2; ++dt)
#pragma unroll
                for (int r = 0; r < 16; ++r) {
                    acc1[dt][r] += c0[dt * 16 + r];
                    acc2[dt][r] += c0[32 + dt * 16 + r];
                }
            l1 += c0[64]; l2 += c0[65];
        }
        __syncthreads();
    }

    if (wv == 0) {
        const float lam = *lamPtr;
        const float inv1 = 1.0f / l1, inv2 = 1.0f / l2;
        float o_[2][16];
        float ss = 0.f;
#pragma unroll
        for (int dt = 0; dt < 2; ++dt)
#pragma unroll
            for (int r = 0; r < 16; ++r) {
                float o = acc1[dt][r] * inv1 - lam * (acc2[dt][r] * inv2);
                o_[dt][r] = o;
                ss += o * o;
            }
        ss += __shfl_xor(ss, 32);
        const float rs = rsqrtf(ss * (1.0f / 64.0f) + 1e-5f);

        u16* aorow = AO + (size_t)(q0 + ql) * D + h * 64;
#pragma unroll
        for (int dt = 0; dt < 2; ++dt)
#pragma unroll
            for (int G = 0; G < 4; ++G) {
                const int dbase = dt * 32 + G * 8 + hi * 4;
                const float4 gv = *(const float4*)&g[dbase];
                u16x4 res;
                res.x = f2bf(o_[dt][4 * G + 0] * rs * gv.x * ONE_MINUS_LI);
                res.y = f2bf(o_[dt][4 * G + 1] * rs * gv.y * ONE_MINUS_LI);
                res.z = f2bf(o_[dt][4 * G + 2] * rs * gv.z * ONE_MINUS_LI);
                res.w = f2bf(o_[dt][4 * G + 3] * rs * gv.w * ONE_MINUS_LI);
                *(u16x4*)&aorow[dbase] = res;
            }
    }
}

// ---------------- launch ----------------
extern "C" void kernel_launch(void* const* d_in, const int* in_sizes, int n_in,
                              void* d_out, int out_size, void* d_ws, size_t ws_size,
                              hipStream_t stream) {
    const float* x   = (const float*)d_in[0];
    const float* Wq  = (const float*)d_in[1];
    const float* Wk  = (const float*)d_in[2];
    const float* Wv  = (const float*)d_in[3];
    const float* Wo  = (const float*)d_in[4];
    const float* lq1 = (const float*)d_in[5];
    const float* lk1 = (const float*)d_in[6];
    const float* lq2 = (const float*)d_in[7];
    const float* lk2 = (const float*)d_in[8];
    const float* g   = (const float*)d_in[9];
    float* out = (float*)d_out;

    char* ws = (char*)d_ws;
    float* cosT = (float*)(ws);                                // 128 KB
    float* sinT = (float*)(ws + 131072);                       // 128 KB
    float* lam  = (float*)(ws + 262144);                       // 256 B
    char*  b    = ws + 262400;
    u16*   Qb   = (u16*)(b);                                   // 4 MB
    u16*   Kb2  = (u16*)(b + 4194304);                         // 4 MB (chunk-tiled planes)
    u16*   VT   = (u16*)(b + 8388608);                         // 4 MB (chunk-tiled planes)
    u16*   AO   = (u16*)(b + 12582912);                        // 4 MB (bf16)
    u16*   xb   = (u16*)(b + 16777216);                        // 4 MB
    u16*   WqT  = (u16*)(b + 20971520);                        // 2 MB
    u16*   WkT  = (u16*)(b + 23068672);                        // 2 MB
    u16*   WvT  = (u16*)(b + 25165824);                        // 2 MB
    u16*   WoT  = (u16*)(b + 27262976);                        // 2 MB

    convert_kernel<<<dim3(2048, 6), 256, 0, stream>>>(x, Wq, Wk, Wv, Wo,
                                                      lq1, lk1, lq2, lk2,
                                                      xb, WqT, WkT, WvT, WoT,
                                                      cosT, sinT, lam);

    mm_kernel<0><<<768, 256, 0, stream>>>(xb, WqT, WkT, WvT, cosT, sinT,
                                          Qb, Kb2, VT, nullptr);

    attn_mfma<<<512, 512, 0, stream>>>(Qb, Kb2, VT, lam, g, AO);

    mm_kernel<1><<<dim3(8, 32), 256, 0, stream>>>(AO, WoT, nullptr, nullptr, cosT, sinT,
                                                  nullptr, nullptr, nullptr, out);
}

// Round 21
// 96.426 us; speedup vs baseline: 1.1858x; 1.0209x over previous
//
#include <hip/hip_runtime.h>
#include <math.h>

#define S 2048
#define D 1024
#define NH 16
#define HD 32
#define HD2 64

static constexpr float SCALE_Q_EXP2  = 0.17677669529663687f * 1.4426950408889634f; // *log2(e)
static constexpr float LAMBDA_INIT_F = 0.78360576653162450f;   // 0.8 - 0.6*exp(-3.6)
static constexpr float ONE_MINUS_LI  = 0.21639423346837553f;

typedef unsigned short u16;
typedef unsigned int   u32;
typedef __attribute__((ext_vector_type(4)))  unsigned short u16x4;
typedef __attribute__((ext_vector_type(8)))  short          bfrag;   // 8 bf16 = 4 VGPR
typedef __attribute__((ext_vector_type(16))) float          f16acc;  // MFMA 32x32 accumulator
typedef __attribute__((ext_vector_type(4)))  unsigned int   uint4v;

__device__ __forceinline__ u16 f2bf(float f) {                 // RNE f32->bf16
    u32 u = __builtin_bit_cast(u32, f);
    return (u16)((u + 0x7FFFu + ((u >> 16) & 1u)) >> 16);
}
__device__ __forceinline__ f16acc fillv(float v) {
    f16acc z;
#pragma unroll
    for (int i = 0; i < 16; ++i) z[i] = v;
    return z;
}
// single-instruction exp2, hazard-safe via builtin (round 14 verified)
__device__ __forceinline__ float exp2_raw(float x) {
#if __has_builtin(__builtin_amdgcn_exp2f)
    return __builtin_amdgcn_exp2f(x);
#else
    float r;
    asm volatile("v_exp_f32 %0, %1\n\ts_nop 1" : "=v"(r) : "v"(x));
    return r;
#endif
}
#define MFMA(a, b, c) __builtin_amdgcn_mfma_f32_32x32x16_bf16(a, b, c, 0, 0, 0)

__device__ __forceinline__ void gload16(const u16* src, u16* lds) {
    __builtin_amdgcn_global_load_lds((const __attribute__((address_space(1))) void*)src,
                                     (__attribute__((address_space(3))) void*)lds, 16, 0, 0);
}

// ---------------- convert (+fused prep): x -> bf16; W -> bf16 transposed; trig tables ----------------
__global__ __launch_bounds__(256)
void convert_kernel(const float* __restrict__ x,  const float* __restrict__ Wq,
                    const float* __restrict__ Wk, const float* __restrict__ Wv,
                    const float* __restrict__ Wo,
                    const float* __restrict__ lq1, const float* __restrict__ lk1,
                    const float* __restrict__ lq2, const float* __restrict__ lk2,
                    u16* __restrict__ xb,  u16* __restrict__ WqT, u16* __restrict__ WkT,
                    u16* __restrict__ WvT, u16* __restrict__ WoT,
                    float* __restrict__ cosT, float* __restrict__ sinT,
                    float* __restrict__ lamOut) {
    const int z = blockIdx.y;
    if (z == 0) {
        const int i = blockIdx.x * 256 + threadIdx.x;
        const float4 v = *(const float4*)&x[(size_t)i * 4];
        u16x4 r; r.x = f2bf(v.x); r.y = f2bf(v.y); r.z = f2bf(v.z); r.w = f2bf(v.w);
        *(u16x4*)&xb[(size_t)i * 4] = r;
        return;
    }
    if (z == 5) {   // fused prep: trig tables (f32-bit-exact numpy pipeline) + lambda
        const int idx = blockIdx.x * 256 + threadIdx.x;
        if (idx < S * 16) {
            int p = idx >> 4;
            int m = idx & 15;
            const double base = (double)1.0e-4f;
            float pf   = (float)pow(base, (double)m * (1.0 / 16.0));
            float freq = 1.0f / pf;
            float angf = (float)p * freq;
            double a = (double)angf;
            cosT[idx] = (float)cos(a);
            sinT[idx] = (float)sin(a);
        }
        if (blockIdx.x == 0 && threadIdx.x == 0) {
            float s1 = 0.f, s2 = 0.f;
            for (int i = 0; i < HD; ++i) {
                s1 += lq1[i] * lk1[i];
                s2 += lq2[i] * lk2[i];
            }
            *lamOut = expf(s1) - expf(s2) + LAMBDA_INIT_F;
        }
        return;
    }
    const int b = blockIdx.x;
    if (b >= 256) return;
    __shared__ u16 Ts[64][66];
    const float* W = (z == 1) ? Wq : (z == 2) ? Wk : (z == 3) ? Wv : Wo;
    u16* T = (z == 1) ? WqT : (z == 2) ? WkT : (z == 3) ? WvT : WoT;
    const int k0 = (b >> 4) * 64, n0 = (b & 15) * 64;
    const int rg = threadIdx.x >> 4, cc = (threadIdx.x & 15) * 4;
#pragma unroll
    for (int i = 0; i < 4; ++i) {
        const int r = rg * 4 + i;
        const float4 v = *(const float4*)&W[(size_t)(k0 + r) * D + n0 + cc];
        Ts[r][cc + 0] = f2bf(v.x); Ts[r][cc + 1] = f2bf(v.y);
        Ts[r][cc + 2] = f2bf(v.z); Ts[r][cc + 3] = f2bf(v.w);
    }
    __syncthreads();
#pragma unroll
    for (int i = 0; i < 4; ++i) {
        const int rn = rg * 4 + i;
        u16x4 res;
        res.x = Ts[cc + 0][rn]; res.y = Ts[cc + 1][rn];
        res.z = Ts[cc + 2][rn]; res.w = Ts[cc + 3][rn];
        *(u16x4*)&T[(size_t)(n0 + rn) * D + k0 + cc] = res;
    }
}

// ---------------- bf16 MFMA GEMM, 64x128 tile, BK=32, 4 waves ----------------
template<int MODE>
__global__ __launch_bounds__(256)
void mm_kernel(const u16* __restrict__ Ab, const u16* __restrict__ B0,
               const u16* __restrict__ B1, const u16* __restrict__ B2,
               const float* __restrict__ cosT, const float* __restrict__ sinT,
               u16* __restrict__ Qb, u16* __restrict__ Kb2, u16* __restrict__ VT,
               float* __restrict__ Of) {
    __shared__ u16 As[64 * 32];      // 4 KB
    __shared__ u16 Bs[128 * 32];     // 8 KB

    int nb, row0;
    if (MODE == 0) {
        const int lid = blockIdx.x;              // 0..767
        const int xcd = lid & 7;
        const int pos = lid >> 3;                // 0..95
        const int nw  = xcd * 96 + pos;
        nb   = nw >> 5;                          // 0..23
        row0 = (nw & 31) * 64;
    } else {
        nb   = blockIdx.x;                       // 0..7
        row0 = blockIdx.y * 64;                  // 0..31 tiles
    }
    const int tid  = threadIdx.x;
    const int wave = tid >> 6;
    const int lane = tid & 63;
    const int ql   = lane & 31;
    const int hi   = lane >> 5;
    const int wr   = wave >> 1;      // 0,1 -> 32-row half
    const int wc   = wave & 1;       // 0,1 -> 64-col half

    const u16* Bt;
    int col0B;
    if (MODE == 0) {
        Bt = (nb < 8) ? B0 : (nb < 16) ? B1 : B2;
        col0B = (nb & 7) * 128;
    } else {
        Bt = B0;
        col0B = nb * 128;
    }

    const int rIn = tid >> 2;                    // 0..63
    const int kof = 8 * (tid & 3);
    const size_t aRow  = (size_t)(row0 + rIn) * D + kof;
    const size_t bRow0 = (size_t)(col0B + rIn) * D + kof;
    const size_t bRow1 = (size_t)(col0B + 64 + rIn) * D + kof;
    u16* ldsA  = &As[8 * tid];
    u16* ldsB0 = &Bs[8 * tid];
    u16* ldsB1 = &Bs[2048 + 8 * tid];

    const int aoff  = (wr * 32 + ql) * 32 + hi * 8;
    const int boff0 = (wc * 64 + ql) * 32 + hi * 8;
    const int boff1 = (wc * 64 + 32 + ql) * 32 + hi * 8;

    f16acc acc0 = fillv(0.f), acc1 = fillv(0.f);

    for (int kk = 0; kk < D; kk += 32) {
        gload16(Ab + aRow + kk, ldsA);
        gload16(Bt + bRow0 + kk, ldsB0);
        gload16(Bt + bRow1 + kk, ldsB1);
        __syncthreads();
#pragma unroll
        for (int ks = 0; ks < 2; ++ks) {
            const bfrag a  = *(const bfrag*)&As[aoff + ks * 16];
            const bfrag b0 = *(const bfrag*)&Bs[boff0 + ks * 16];
            const bfrag b1 = *(const bfrag*)&Bs[boff1 + ks * 16];
            acc0 = MFMA(a, b0, acc0);
            acc1 = MFMA(a, b1, acc1);
        }
        __syncthreads();
    }

    f16acc accA[2];
    accA[0] = acc0; accA[1] = acc1;

    if (MODE == 0 && nb < 8) {           // Q: RoPE + scale, row layout
        const int m = ql >> 1;
        const bool ev = (ql & 1) == 0;
#pragma unroll
        for (int j = 0; j < 2; ++j) {
            const int n = (nb & 7) * 128 + wc * 64 + j * 32 + ql;
            const int head = n >> 5;
            u16* hb = Qb + (size_t)head * S * HD;
#pragma unroll
            for (int r = 0; r < 16; ++r) {
                const int row = row0 + wr * 32 + 4 * hi + (r & 3) + 8 * (r >> 2);
                const float self = accA[j][r];
                const float part = __shfl_xor(self, 1);
                const float c = cosT[(row << 4) + m], s = sinT[(row << 4) + m];
                const float res = ev ? (self * c - part * s) : (part * s + self * c);
                hb[(size_t)row * HD + ql] = f2bf(res * SCALE_Q_EXP2);
            }
        }
    } else if (MODE == 0 && nb < 16) {   // K: RoPE, chunk-tiled dim-octet planes
        const int m = ql >> 1;
        const bool ev = (ql & 1) == 0;
#pragma unroll
        for (int j = 0; j < 2; ++j) {
            const int n = (nb & 7) * 128 + wc * 64 + j * 32 + ql;
            const int h2 = n >> 5;
            const int d  = n & 31;
            const int dpl = (d >> 3) * 256 + (d & 7);
            u16* hb = Kb2 + (size_t)h2 * 65536;          // 64 chunks x 1024 u16
#pragma unroll
            for (int r = 0; r < 16; ++r) {
                const int row = row0 + wr * 32 + 4 * hi + (r & 3) + 8 * (r >> 2);
                const float self = accA[j][r];
                const float part = __shfl_xor(self, 1);
                const float c = cosT[(row << 4) + m], s = sinT[(row << 4) + m];
                const float res = ev ? (self * c - part * s) : (part * s + self * c);
                hb[(row >> 5) * 1024 + dpl + (row & 31) * 8] = f2bf(res);
            }
        }
    } else if (MODE == 0) {              // V -> VT2: chunk-tiled (dt,key-octet) planes
#pragma unroll
        for (int j = 0; j < 2; ++j) {
            const int n = (nb & 7) * 128 + wc * 64 + j * 32 + ql;   // global col 0..1023
            const int head = n >> 6, d = n & 63;
            const int dt = d >> 5, dl = d & 31;
            u16* tb = VT + (size_t)head * 131072;                   // 64 chunks x 2048 u16
#pragma unroll
            for (int q = 0; q < 4; ++q) {
                const int row = row0 + wr * 32 + 4 * hi + 8 * q;    // key, 4 consecutive
                const int idx = (row >> 5) * 2048 + (dt * 4 + q) * 256 + dl * 8 + 4 * hi;
                u16x4 res;
                res.x = f2bf(accA[j][4 * q + 0]);
                res.y = f2bf(accA[j][4 * q + 1]);
                res.z = f2bf(accA[j][4 * q + 2]);
                res.w = f2bf(accA[j][4 * q + 3]);
                *(u16x4*)&tb[idx] = res;
            }
        }
    } else {
#pragma unroll
        for (int j = 0; j < 2; ++j) {
            const int gcol = col0B + wc * 64 + j * 32 + ql;
#pragma unroll
            for (int r = 0; r < 16; ++r) {
                const int row = row0 + wr * 32 + 4 * hi + (r & 3) + 8 * (r >> 2);
                Of[(size_t)row * D + gcol] = accA[j][r];
            }
        }
    }
}

// ---------------- MFMA differential flash attention ----------------
// R17 structure with sub-head phase interleave: SM1 -> PV1 -> SM2 -> PV2, so each
// sub-head's PV (MFMA pipe) executes underneath the other's exp2 block (TRANS pipe).
// l-reads moved to body end (no AGPR-read stall between phases). Data flow identical.
__global__ __launch_bounds__(512, 2)
void attn_mfma(const u16* __restrict__ Qb, const u16* __restrict__ Kb2,
               const u16* __restrict__ Vt2, const float* __restrict__ lamPtr,
               const float* __restrict__ g, u16* __restrict__ AO) {
    const int bid  = blockIdx.x;
    const int h    = (bid & 7) * 2 + ((bid >> 3) >> 5);   // head-affinity: XCD k owns heads {2k,2k+1}
    const int bx   = (bid >> 3) & 31;
    const int tid  = threadIdx.x;
    const int wave = tid >> 6;
    const int lane = tid & 63;
    const int hi   = lane >> 5;
    const int ql   = lane & 31;
    const int t    = wave >> 2;          // q-tile in block (0..1)
    const int wv   = wave & 3;           // kv-quarter (0..3)
    const int q0   = (bx * 2 + t) * 32;
    const int cbase = wv * 16;           // 16 chunks of 32 keys each

    __shared__ float CMB[2][64][66];     // 33.8 KB merge buffer

    const u16* qp1 = Qb + ((size_t)(2 * h) * S + q0 + ql) * HD + 8 * hi;
    const u16* qp2 = qp1 + (size_t)S * HD;
    bfrag qf1[2], qf2[2];
    qf1[0] = *(const bfrag*)(qp1);      qf1[1] = *(const bfrag*)(qp1 + 16);
    qf2[0] = *(const bfrag*)(qp2);      qf2[1] = *(const bfrag*)(qp2 + 16);

    const u16* k1g = Kb2 + (size_t)(2 * h) * 65536;      // + c*1024
    const u16* k2g = k1g + 65536;
    const u16* vg  = Vt2 + (size_t)h * 131072;           // + c*2048
    const int kro  = ql * 8;                             // lane offset within a plane

    const f16acc ZR = fillv(0.f);
    uint4v ou; ou[0] = ou[1] = ou[2] = ou[3] = 0x3F803F80u;   // bf16 1.0 pairs
    const bfrag ONES = __builtin_bit_cast(bfrag, ou);

    f16acc acc1[2], acc2[2];
    acc1[0] = fillv(0.f); acc1[1] = fillv(0.f);
    acc2[0] = fillv(0.f); acc2[1] = fillv(0.f);
    float l1 = 0.f, l2 = 0.f;

    bfrag kA1[2], kA2[2], kB1[2], kB2[2];
    bfrag vA[2][2], vB[2][2];
#pragma unroll
    for (int s = 0; s < 2; ++s) {
        kA1[s] = *(const bfrag*)(k1g + (size_t)cbase * 1024 + (2 * s + hi) * 256 + kro);
        kA2[s] = *(const bfrag*)(k2g + (size_t)cbase * 1024 + (2 * s + hi) * 256 + kro);
#pragma unroll
        for (int dt = 0; dt < 2; ++dt)
            vA[s][dt] = *(const bfrag*)(vg + (size_t)cbase * 2048 + (dt * 4 + 2 * s + hi) * 256 + kro);
    }

    auto body = [&](bfrag (&kc1)[2], bfrag (&kc2)[2], bfrag (&vc)[2][2],
                    bfrag (&kn1)[2], bfrag (&kn2)[2], bfrag (&vn)[2][2], int cn) {
        // prefetch next chunk (contiguous full-line loads)
        const u16* k1c = k1g + (size_t)cn * 1024;
        const u16* k2c = k2g + (size_t)cn * 1024;
        const u16* vvc = vg + (size_t)cn * 2048;
#pragma unroll
        for (int s = 0; s < 2; ++s) {
            kn1[s] = *(const bfrag*)(k1c + (2 * s + hi) * 256 + kro);
            kn2[s] = *(const bfrag*)(k2c + (2 * s + hi) * 256 + kro);
#pragma unroll
            for (int dt = 0; dt < 2; ++dt)
                vn[s][dt] = *(const bfrag*)(vvc + (dt * 4 + 2 * s + hi) * 256 + kro);
        }

        // QK both sub-heads (independent -> fill MFMA pipe; QK2 runs under SM1)
        __builtin_amdgcn_s_setprio(1);
        f16acc s1 = MFMA(kc1[0], qf1[0], ZR);  s1 = MFMA(kc1[1], qf1[1], s1);
        f16acc s2 = MFMA(kc2[0], qf2[0], ZR);  s2 = MFMA(kc2[1], qf2[1], s2);
        __builtin_amdgcn_s_setprio(0);

        // ---- SM1 ----
#pragma unroll
        for (int r = 0; r < 16; ++r) s1[r] = exp2_raw(s1[r]);
        u32 w1[8];
#pragma unroll
        for (int j = 0; j < 8; ++j)
            asm("v_cvt_pk_bf16_f32 %0, %1, %2" : "=v"(w1[j]) : "v"(s1[2 * j]), "v"(s1[2 * j + 1]));
        asm("v_permlane32_swap_b32 %0, %1" : "+v"(w1[0]), "+v"(w1[2]));
        asm("v_permlane32_swap_b32 %0, %1" : "+v"(w1[1]), "+v"(w1[3]));
        asm("v_permlane32_swap_b32 %0, %1" : "+v"(w1[4]), "+v"(w1[6]));
        asm("v_permlane32_swap_b32 %0, %1" : "+v"(w1[5]), "+v"(w1[7]));
        uint4v u;
        bfrag p1[2];
        u[0] = w1[0]; u[1] = w1[1]; u[2] = w1[2]; u[3] = w1[3];
        p1[0] = __builtin_bit_cast(bfrag, u);
        u[0] = w1[4]; u[1] = w1[5]; u[2] = w1[6]; u[3] = w1[7];
        p1[1] = __builtin_bit_cast(bfrag, u);

        // ---- PV1 (+ones1): executes under SM2's TRANS block below ----
        __builtin_amdgcn_s_setprio(1);
        acc1[0] = MFMA(vc[0][0], p1[0], acc1[0]);
        acc1[0] = MFMA(vc[1][0], p1[1], acc1[0]);
        acc1[1] = MFMA(vc[0][1], p1[0], acc1[1]);
        acc1[1] = MFMA(vc[1][1], p1[1], acc1[1]);
        f16acc t1 = MFMA(ONES, p1[0], ZR);  t1 = MFMA(ONES, p1[1], t1);
        __builtin_amdgcn_s_setprio(0);

        // ---- SM2 ----
#pragma unroll
        for (int r = 0; r < 16; ++r) s2[r] = exp2_raw(s2[r]);
        u32 w2[8];
#pragma unroll
        for (int j = 0; j < 8; ++j)
            asm("v_cvt_pk_bf16_f32 %0, %1, %2" : "=v"(w2[j]) : "v"(s2[2 * j]), "v"(s2[2 * j + 1]));
        asm("v_permlane32_swap_b32 %0, %1" : "+v"(w2[0]), "+v"(w2[2]));
        asm("v_permlane32_swap_b32 %0, %1" : "+v"(w2[1]), "+v"(w2[3]));
        asm("v_permlane32_swap_b32 %0, %1" : "+v"(w2[4]), "+v"(w2[6]));
        asm("v_permlane32_swap_b32 %0, %1" : "+v"(w2[5]), "+v"(w2[7]));
        bfrag p2[2];
        u[0] = w2[0]; u[1] = w2[1]; u[2] = w2[2]; u[3] = w2[3];
        p2[0] = __builtin_bit_cast(bfrag, u);
        u[0] = w2[4]; u[1] = w2[5]; u[2] = w2[6]; u[3] = w2[7];
        p2[1] = __builtin_bit_cast(bfrag, u);

        // ---- PV2 (+ones2) ----
        __builtin_amdgcn_s_setprio(1);
        acc2[0] = MFMA(vc[0][0], p2[0], acc2[0]);
        acc2[0] = MFMA(vc[1][0], p2[1], acc2[0]);
        acc2[1] = MFMA(vc[0][1], p2[0], acc2[1]);
        acc2[1] = MFMA(vc[1][1], p2[1], acc2[1]);
        f16acc t2 = MFMA(ONES, p2[0], ZR);  t2 = MFMA(ONES, p2[1], t2);
        __builtin_amdgcn_s_setprio(0);

        // l-reads at body end (t1 long complete; t2 is the only fresh wait)
        l1 += t1[0];
        l2 += t2[0];
    };

    // explicit 2x unroll ping-pong on K and V (no rotate movs)
    for (int i = 0; i < 16; i += 2) {
        const int c0 = cbase + i;
        body(kA1, kA2, vA, kB1, kB2, vB, c0 + 1);
        const int c2 = (i + 2 < 16) ? c0 + 2 : c0 + 1;
        body(kB1, kB2, vB, kA1, kA2, vA, c2);
    }

    // ---- merge the 4 kv-quarters: pure addition ----
#pragma unroll 1
    for (int p = 1; p < 4; ++p) {
        if (wv == p) {
            float* c0 = &CMB[t][lane][0];
#pragma unroll
            for (int dt = 0; dt < 2; ++dt)
#pragma unroll
                for (int r = 0; r < 16; ++r) {
                    c0[dt * 16 + r]      = acc1[dt][r];
                    c0[32 + dt * 16 + r] = acc2[dt][r];
                }
            c0[64] = l1; c0[65] = l2;
        }
        __syncthreads();
        if (wv == 0) {
            const float* c0 = &CMB[t][lane][0];
#pragma unroll
            for (int dt = 0; dt < 2; ++dt)
#pragma unroll
                for (int r = 0; r < 16; ++r) {
                    acc1[dt][r] += c0[dt * 16 + r];
                    acc2[dt][r] += c0[32 + dt * 16 + r];
                }
            l1 += c0[64]; l2 += c0[65];
        }
        __syncthreads();
    }

    if (wv == 0) {
        const float lam = *lamPtr;
        const float inv1 = 1.0f / l1, inv2 = 1.0f / l2;
        float o_[2][16];
        float ss = 0.f;
#pragma unroll
        for (int dt = 0; dt < 2; ++dt)
#pragma unroll
            for (int r = 0; r < 16; ++r) {
                float o = acc1[dt][r] * inv1 - lam * (acc2[dt][r] * inv2);
                o_[dt][r] = o;
                ss += o * o;
            }
        ss += __shfl_xor(ss, 32);
        const float rs = rsqrtf(ss * (1.0f / 64.0f) + 1e-5f);

        u16* aorow = AO + (size_t)(q0 + ql) * D + h * 64;
#pragma unroll
        for (int dt = 0; dt < 2; ++dt)
#pragma unroll
            for (int G = 0; G < 4; ++G) {
                const int dbase = dt * 32 + G * 8 + hi * 4;
                const float4 gv = *(const float4*)&g[dbase];
                u16x4 res;
                res.x = f2bf(o_[dt][4 * G + 0] * rs * gv.x * ONE_MINUS_LI);
                res.y = f2bf(o_[dt][4 * G + 1] * rs * gv.y * ONE_MINUS_LI);
                res.z = f2bf(o_[dt][4 * G + 2] * rs * gv.z * ONE_MINUS_LI);
                res.w = f2bf(o_[dt][4 * G + 3] * rs * gv.w * ONE_MINUS_LI);
                *(u16x4*)&aorow[dbase] = res;
            }
    }
}

// ---------------- launch ----------------
extern "C" void kernel_launch(void* const* d_in, const int* in_sizes, int n_in,
                              void* d_out, int out_size, void* d_ws, size_t ws_size,
                              hipStream_t stream) {
    const float* x   = (const float*)d_in[0];
    const float* Wq  = (const float*)d_in[1];
    const float* Wk  = (const float*)d_in[2];
    const float* Wv  = (const float*)d_in[3];
    const float* Wo  = (const float*)d_in[4];
    const float* lq1 = (const float*)d_in[5];
    const float* lk1 = (const float*)d_in[6];
    const float* lq2 = (const float*)d_in[7];
    const float* lk2 = (const float*)d_in[8];
    const float* g   = (const float*)d_in[9];
    float* out = (float*)d_out;

    char* ws = (char*)d_ws;
    float* cosT = (float*)(ws);                                // 128 KB
    float* sinT = (float*)(ws + 131072);                       // 128 KB
    float* lam  = (float*)(ws + 262144);                       // 256 B
    char*  b    = ws + 262400;
    u16*   Qb   = (u16*)(b);                                   // 4 MB
    u16*   Kb2  = (u16*)(b + 4194304);                         // 4 MB (chunk-tiled planes)
    u16*   VT   = (u16*)(b + 8388608);                         // 4 MB (chunk-tiled planes)
    u16*   AO   = (u16*)(b + 12582912);                        // 4 MB (bf16)
    u16*   xb   = (u16*)(b + 16777216);                        // 4 MB
    u16*   WqT  = (u16*)(b + 20971520);                        // 2 MB
    u16*   WkT  = (u16*)(b + 23068672);                        // 2 MB
    u16*   WvT  = (u16*)(b + 25165824);                        // 2 MB
    u16*   WoT  = (u16*)(b + 27262976);                        // 2 MB

    convert_kernel<<<dim3(2048, 6), 256, 0, stream>>>(x, Wq, Wk, Wv, Wo,
                                                      lq1, lk1, lq2, lk2,
                                                      xb, WqT, WkT, WvT, WoT,
                                                      cosT, sinT, lam);

    mm_kernel<0><<<768, 256, 0, stream>>>(xb, WqT, WkT, WvT, cosT, sinT,
                                          Qb, Kb2, VT, nullptr);

    attn_mfma<<<512, 512, 0, stream>>>(Qb, Kb2, VT, lam, g, AO);

    mm_kernel<1><<<dim3(8, 32), 256, 0, stream>>>(AO, WoT, nullptr, nullptr, cosT, sinT,
                                                  nullptr, nullptr, nullptr, out);
}